// Round 13
// baseline (289.653 us; speedup 1.0000x reference)
//
#include <hip/hip_runtime.h>
#include <hip/hip_bf16.h>

#define NS 128
#define NV 64
#define TPC 192
#define NBASIS 16
#define HID 128
#define WOUT 384
#define NNODE 16000
#define NEDGE 256000
#define EPB 32
#define GVPLANE 3072000   // 16000*192
#define VPLANE  1024000   // 16000*64

typedef __attribute__((ext_vector_type(8))) short bf16x8;
typedef __attribute__((ext_vector_type(8))) unsigned short u16x8;
typedef __attribute__((ext_vector_type(4))) unsigned short u16x4;
typedef __attribute__((ext_vector_type(4))) float f32x4;

__device__ __forceinline__ float silu_f(float x) { return x / (1.0f + __expf(-x)); }
__device__ __forceinline__ unsigned short bf16b(float x) {
  __hip_bfloat16 h = __float2bfloat16(x);
  return *reinterpret_cast<unsigned short*>(&h);
}
__device__ __forceinline__ float bf2f(unsigned short u) {
  return __uint_as_float(((unsigned)u) << 16);
}

// ------- pack W1/W2/Wqs/Wqv into MFMA B-fragment order (bf16); zero cursor ----
__global__ __launch_bounds__(256) void pack_weights(
    const float* __restrict__ W1, const float* __restrict__ W2,
    const float* __restrict__ Wqs, const float* __restrict__ Wqv,
    unsigned short* __restrict__ W1P, unsigned short* __restrict__ W2P,
    unsigned short* __restrict__ WqsP, unsigned short* __restrict__ WqvP,
    int* __restrict__ cursor) {
  const int id = blockIdx.x * 256 + threadIdx.x;
  const int j = id & 7, lane = (id >> 3) & 63;
  const int kj = (lane >> 4) * 8 + j;       // k-offset within 32-chunk
  const int nc = lane & 15;                 // col within 16-tile
  if (id < NNODE) cursor[id] = 0;           // replaces hipMemsetAsync
  if (id < 24 * 4 * 64 * 8) {               // W2P[nt24][kc4][lane][8]
    const int kc = (id >> 9) & 3, nt = id >> 11;
    W2P[id] = bf16b(W2[(kc * 32 + kj) * WOUT + nt * 16 + nc]);
  }
  if (id < 8 * 64 * 8) {                    // W1P[nt8][lane][8] (K=16 padded to 32)
    const int nt = id >> 9;
    W1P[id] = (kj < NBASIS) ? bf16b(W1[kj * HID + nt * 16 + nc]) : (unsigned short)0;
  }
  if (id < 8 * 6 * 64 * 8) {                // WqsP[nt8][kc6][lane][8]
    const int kc = (id >> 9) % 6, nt = id / (6 * 512);
    WqsP[id] = bf16b(Wqs[(kc * 32 + kj) * NS + nt * 16 + nc]);
  }
  if (id < 4 * 6 * 64 * 8) {                // WqvP[nt4][kc6][lane][8]
    const int kc = (id >> 9) % 6, nt = id / (6 * 512);
    WqvP[id] = bf16b(Wqv[(kc * 32 + kj) * NV + nt * 16 + nc]);
  }
}

// -------- node_pre: 4 nodes/block; also emits bf16 x_s16 and xv16 planes ------
__global__ __launch_bounds__(256) void node_pre4(
    const float* __restrict__ node_feat, const float* __restrict__ Wps,
    const float* __restrict__ bps, const float* __restrict__ Wpv,
    float* __restrict__ x_s, float* __restrict__ x_v,
    unsigned short* __restrict__ x_s16, unsigned short* __restrict__ xv16) {
  const int n0 = blockIdx.x * 4;
  const int t = threadIdx.x;
  __shared__ float s_sh[4][NS];
  __shared__ float v_sh[4][NV * 3];
  for (int i = t; i < 4 * 320; i += 256) {
    const int nn = i / 320, off = i - nn * 320;
    const float val = node_feat[(size_t)(n0 + nn) * 320 + off];
    if (off < NS) s_sh[nn][off] = val; else v_sh[nn][off - NS] = val;
  }
  __syncthreads();
  for (int o = t; o < 320; o += 256) {
    if (o < NS) {
      float a0 = 0.f, a1 = 0.f, a2 = 0.f, a3 = 0.f;
      #pragma unroll 8
      for (int u = 0; u < NS; ++u) {
        const float wv = Wps[u * NS + o];
        a0 = fmaf(s_sh[0][u], wv, a0); a1 = fmaf(s_sh[1][u], wv, a1);
        a2 = fmaf(s_sh[2][u], wv, a2); a3 = fmaf(s_sh[3][u], wv, a3);
      }
      const float b = bps[o];
      const float r0 = a0 * 0.08838834764831845f + b;
      const float r1 = a1 * 0.08838834764831845f + b;
      const float r2 = a2 * 0.08838834764831845f + b;
      const float r3 = a3 * 0.08838834764831845f + b;
      x_s[(size_t)(n0 + 0) * NS + o] = r0; x_s16[(size_t)(n0 + 0) * NS + o] = bf16b(r0);
      x_s[(size_t)(n0 + 1) * NS + o] = r1; x_s16[(size_t)(n0 + 1) * NS + o] = bf16b(r1);
      x_s[(size_t)(n0 + 2) * NS + o] = r2; x_s16[(size_t)(n0 + 2) * NS + o] = bf16b(r2);
      x_s[(size_t)(n0 + 3) * NS + o] = r3; x_s16[(size_t)(n0 + 3) * NS + o] = bf16b(r3);
    } else {
      const int q = o - NS;
      const int vch = q / 3, c = q - vch * 3;
      float a0 = 0.f, a1 = 0.f, a2 = 0.f, a3 = 0.f;
      #pragma unroll 8
      for (int u = 0; u < NV; ++u) {
        const float wv = Wpv[u * NV + vch];
        a0 = fmaf(v_sh[0][u * 3 + c], wv, a0); a1 = fmaf(v_sh[1][u * 3 + c], wv, a1);
        a2 = fmaf(v_sh[2][u * 3 + c], wv, a2); a3 = fmaf(v_sh[3][u * 3 + c], wv, a3);
      }
      const float r0 = a0 * 0.125f, r1 = a1 * 0.125f, r2 = a2 * 0.125f, r3 = a3 * 0.125f;
      x_v[(size_t)(n0 + 0) * (NV * 3) + q] = r0;
      x_v[(size_t)(n0 + 1) * (NV * 3) + q] = r1;
      x_v[(size_t)(n0 + 2) * (NV * 3) + q] = r2;
      x_v[(size_t)(n0 + 3) * (NV * 3) + q] = r3;
      unsigned short* pl = xv16 + (size_t)c * VPLANE;
      pl[(size_t)(n0 + 0) * NV + vch] = bf16b(r0);
      pl[(size_t)(n0 + 1) * NV + vch] = bf16b(r1);
      pl[(size_t)(n0 + 2) * NV + vch] = bf16b(r2);
      pl[(size_t)(n0 + 3) * NV + vch] = bf16b(r3);
    }
  }
}

// ================= CSR build =================
__global__ void hist_kernel(const int* __restrict__ ei, int* __restrict__ cnt) {
  int e = blockIdx.x * 256 + threadIdx.x;
  if (e < NEDGE) atomicAdd(&cnt[ei[e]], 1);
}

__global__ __launch_bounds__(256) void scan_kernel(
    const int* __restrict__ cnt, int* __restrict__ row_start, int* __restrict__ cursor) {
  __shared__ int part[256];
  const int t = threadIdx.x;
  const int base = t * 63;
  int s = 0;
  for (int i = 0; i < 63; ++i) {
    int idx = base + i;
    if (idx < NNODE) s += cnt[idx];
  }
  part[t] = s;
  __syncthreads();
  if (t == 0) {
    int run = 0;
    for (int i = 0; i < 256; ++i) { int x = part[i]; part[i] = run; run += x; }
  }
  __syncthreads();
  int run = part[t];
  for (int i = 0; i < 63; ++i) {
    int idx = base + i;
    if (idx < NNODE) {
      int c = cnt[idx];   // read before overwrite (cnt aliases cursor)
      row_start[idx] = run;
      cursor[idx] = run;
      run += c;
    }
  }
  if (t == 255) row_start[NNODE] = run;
}

__global__ void scatter_kernel(const int* __restrict__ ei,
                               const float* __restrict__ edge_rshs,
                               int* __restrict__ cursor, int* __restrict__ perm,
                               float4* __restrict__ meta) {
  int e = blockIdx.x * 256 + threadIdx.x;
  if (e < NEDGE) {
    int p = atomicAdd(&cursor[ei[e]], 1);
    perm[e] = p;
    float4 m;
    m.x = __int_as_float(ei[NEDGE + e]);
    m.y = edge_rshs[e * 4 + 1];
    m.z = edge_rshs[e * 4 + 2];
    m.w = edge_rshs[e * 4 + 3];
    meta[p] = m;
  }
}

// ================= edge MLP via MFMA -> bf16 messages at CSR slots ============
// De-unioned msgb: waves decouple from the staging barrier through GEMM2+epilogue
// (each wave writes only its own 96-col msgb slice). 3 barriers total.
__global__ __launch_bounds__(256) void edge_mlp_mfma(
    const float* __restrict__ edge_attr, const float* __restrict__ edge_rshs,
    const int* __restrict__ edge_index, const int* __restrict__ perm,
    const unsigned short* __restrict__ W1P, const float* __restrict__ b1,
    const unsigned short* __restrict__ W2P, const float* __restrict__ b2,
    const unsigned short* __restrict__ x_s16, const unsigned short* __restrict__ xv16,
    unsigned short* __restrict__ msg) {
  __shared__ __align__(16) unsigned short ea[32 * 48];
  __shared__ __align__(16) unsigned short Hs[32 * 136];
  __shared__ __align__(16) unsigned short msgb[32 * 392];
  __shared__ __align__(16) unsigned short sj[32][136];
  __shared__ __align__(16) unsigned short vd[32][72];
  __shared__ unsigned short b2s[384];
  __shared__ unsigned short b1s[128];
  __shared__ int src_sh[32];
  __shared__ int slot_sh[32];
  __shared__ float rsh_sh[32][4];
  const int t = threadIdx.x;
  const int lane = t & 63;
  const int w = t >> 6;
  const int l15 = lane & 15;
  const int l4 = lane >> 4;
  const int eblk = blockIdx.x * EPB;

  // ---- phase 0: metadata + bias staging + vectorized ea staging
  if (t < 32 * 4) rsh_sh[t >> 2][t & 3] = edge_rshs[(size_t)eblk * 4 + t];
  if (t < 32) {
    src_sh[t] = edge_index[NEDGE + eblk + t];
    slot_sh[t] = perm[eblk + t];
  }
  for (int i = t; i < 384; i += 256) b2s[i] = bf16b(b2[i]);
  if (t < 128) b1s[t] = bf16b(b1[t]);
  if (t < 128) {
    const int e = t >> 2, q = t & 3;
    const float4 v = *(const float4*)&edge_attr[(size_t)(eblk + e) * NBASIS + q * 4];
    u16x4 tmp;
    tmp[0] = bf16b(v.x); tmp[1] = bf16b(v.y); tmp[2] = bf16b(v.z); tmp[3] = bf16b(v.w);
    *(u16x4*)&ea[e * 48 + q * 4] = tmp;
  } else {
    const int idx = t - 128;           // 128 chunks × 8 shorts of K-pad
    const int e = idx >> 2, q = idx & 3;
    *(u16x8*)&ea[e * 48 + 16 + q * 8] = (u16x8){0, 0, 0, 0, 0, 0, 0, 0};
  }
  __syncthreads();   // barrier 1

  // ---- phase 1: GEMM1 (H = silu(ea@W1+b1)) + sj/vd staging from bf16 sources
  {
    const int mt = w & 1, ch = w >> 1;
    const bf16x8 afrag = *(const bf16x8*)&ea[(mt * 16 + l15) * 48 + l4 * 8];
    #pragma unroll
    for (int nt = 0; nt < 4; ++nt) {
      const int ntg = ch * 4 + nt;
      const bf16x8 bfrag = *(const bf16x8*)&W1P[((size_t)ntg * 64 + lane) * 8];
      f32x4 d = {0.f, 0.f, 0.f, 0.f};
      d = __builtin_amdgcn_mfma_f32_16x16x32_bf16(afrag, bfrag, d, 0, 0, 0);
      const int col = ntg * 16 + l15;
      const float bias = bf2f(b1s[col]);
      #pragma unroll
      for (int i = 0; i < 4; ++i) {
        const int e = mt * 16 + l4 * 4 + i;
        Hs[e * 136 + col] = bf16b(silu_f(d[i] + bias));
      }
    }
  }
  // sj: straight u16x8 copy from x_s16 (no conversions)
  #pragma unroll
  for (int p = 0; p < 2; ++p) {
    const int idx = p * 256 + t;
    const int e = idx >> 4, c8 = idx & 15;
    *(u16x8*)&sj[e][c8 * 8] =
        *(const u16x8*)&x_s16[(size_t)src_sh[e] * NS + c8 * 8];
  }
  // vd[e][u] = <v_j[u], r1> * inv_sqrt3 from bf16 planes
  #pragma unroll
  for (int p = 0; p < 8; ++p) {
    const int idx = p * 256 + t;
    const int e = idx >> 6, u = idx & 63;
    const size_t base = (size_t)src_sh[e] * NV + u;
    const float v0 = bf2f(xv16[base]);
    const float v1 = bf2f(xv16[VPLANE + base]);
    const float v2 = bf2f(xv16[2 * VPLANE + base]);
    const float dotv = fmaf(v0, rsh_sh[e][1], fmaf(v1, rsh_sh[e][2], v2 * rsh_sh[e][3]));
    vd[e][u] = bf16b(dotv * 0.5773502691896258f);
  }
  __syncthreads();   // barrier 2 — waves decoupled from here to barrier 3

  // ---- phase 2: preload A-frags from Hs (no barrier needed — Hs is read-only now)
  bf16x8 afr[2][4];
  #pragma unroll
  for (int mt = 0; mt < 2; ++mt)
    #pragma unroll
    for (int k = 0; k < 4; ++k)
      afr[mt][k] = *(const bf16x8*)&Hs[(mt * 16 + l15) * 136 + k * 32 + l4 * 8];

  float r0a[2][4];
  #pragma unroll
  for (int mt = 0; mt < 2; ++mt)
    #pragma unroll
    for (int i = 0; i < 4; ++i) r0a[mt][i] = rsh_sh[mt * 16 + l4 * 4 + i][0];

  // ---- phase 3: GEMM2 + in-LDS epilogue; wave w owns its own 96-col msgb slice
  #pragma unroll
  for (int nn = 0; nn < 6; ++nn) {
    const int nt = w * 6 + nn;
    bf16x8 bfr[4];
    #pragma unroll
    for (int k = 0; k < 4; ++k)
      bfr[k] = *(const bf16x8*)&W2P[(((size_t)nt * 4 + k) * 64 + lane) * 8];
    f32x4 acc0 = {0.f, 0.f, 0.f, 0.f}, acc1 = {0.f, 0.f, 0.f, 0.f};
    #pragma unroll
    for (int k = 0; k < 4; ++k) {
      acc0 = __builtin_amdgcn_mfma_f32_16x16x32_bf16(afr[0][k], bfr[k], acc0, 0, 0, 0);
      acc1 = __builtin_amdgcn_mfma_f32_16x16x32_bf16(afr[1][k], bfr[k], acc1, 0, 0, 0);
    }
    const int col = nt * 16 + l15;
    const float bias = bf2f(b2s[col]);
    if (col < NS) {
      #pragma unroll
      for (int mt = 0; mt < 2; ++mt)
        #pragma unroll
        for (int i = 0; i < 4; ++i) {
          const int e = mt * 16 + l4 * 4 + i;
          const float wv = (mt ? acc1[i] : acc0[i]) + bias;
          msgb[e * 392 + col] = bf16b(wv * bf2f(sj[e][col]) * r0a[mt][i]);
        }
    } else if (col < NS + NV) {
      const int u = col - NS;
      #pragma unroll
      for (int mt = 0; mt < 2; ++mt)
        #pragma unroll
        for (int i = 0; i < 4; ++i) {
          const int e = mt * 16 + l4 * 4 + i;
          const float wv = (mt ? acc1[i] : acc0[i]) + bias;
          msgb[e * 392 + col] = bf16b(wv * bf2f(vd[e][u]));
        }
    } else if (col < 2 * NS + NV) {
      const int sjc = col - (NS + NV);
      #pragma unroll
      for (int mt = 0; mt < 2; ++mt)
        #pragma unroll
        for (int i = 0; i < 4; ++i) {
          const int e = mt * 16 + l4 * 4 + i;
          const float wv = (mt ? acc1[i] : acc0[i]) + bias;
          msgb[e * 392 + col] = bf16b(wv * bf2f(sj[e][sjc]));
        }
    } else {
      #pragma unroll
      for (int mt = 0; mt < 2; ++mt)
        #pragma unroll
        for (int i = 0; i < 4; ++i) {
          const int e = mt * 16 + l4 * 4 + i;
          const float wv = (mt ? acc1[i] : acc0[i]) + bias;
          msgb[e * 392 + col] = bf16b(wv * r0a[mt][i]);
        }
    }
  }
  __syncthreads();   // barrier 3

  // ---- phase 4: coalesced write-out, 768 B per edge row at its CSR slot
  #pragma unroll
  for (int p = 0; p < 6; ++p) {
    const int idx = p * 256 + t;
    const int e = idx / 48, c = idx - e * 48;
    const u16x8 vv = *(const u16x8*)&msgb[e * 392 + c * 8];
    *(u16x8*)&msg[(size_t)slot_sh[e] * 384 + c * 8] = vv;
  }
}

// ===== node_gather: 4 role-waves, batch-8 unrolled loads ======================
// role 0: cols {2ln, 2ln+1} (one dword) + {128+ln}
// role 1/2: kind1 rows u=(role-1)*64+ln  (FMA with r1)
// role 3:   kind2 rows u=128+ln          (FMA with xv16 planes)
__global__ __launch_bounds__(256) void node_gather(
    const unsigned short* __restrict__ msg, const int* __restrict__ row_start,
    const float4* __restrict__ meta, const unsigned short* __restrict__ xv16,
    unsigned short* __restrict__ gs16, unsigned short* __restrict__ gv16) {
  const int n = blockIdx.x;
  const int t = threadIdx.x;
  const int role = t >> 6, ln = t & 63;
  const int beg = row_start[n], end = row_start[n + 1];

  float a0 = 0.f, a1 = 0.f, a2 = 0.f;

  if (role == 0) {
    const unsigned short* mp = msg + (size_t)beg * 384;
    int i = beg;
    for (; i + 8 <= end; i += 8, mp += 3072) {
      unsigned int pr[8]; unsigned short v2[8];
      #pragma unroll
      for (int u = 0; u < 8; ++u) {
        pr[u] = *(const unsigned int*)(mp + u * 384 + 2 * ln);
        v2[u] = mp[u * 384 + 128 + ln];
      }
      #pragma unroll
      for (int u = 0; u < 8; ++u) {
        a0 += __uint_as_float(pr[u] << 16);
        a1 += __uint_as_float(pr[u] & 0xffff0000u);
        a2 += bf2f(v2[u]);
      }
    }
    for (; i < end; ++i, mp += 384) {
      const unsigned int p = *(const unsigned int*)(mp + 2 * ln);
      a0 += __uint_as_float(p << 16);
      a1 += __uint_as_float(p & 0xffff0000u);
      a2 += bf2f(mp[128 + ln]);
    }
    gs16[(size_t)n * 192 + 2 * ln]     = bf16b(silu_f(a0));
    gs16[(size_t)n * 192 + 2 * ln + 1] = bf16b(silu_f(a1));
    gs16[(size_t)n * 192 + 128 + ln]   = bf16b(silu_f(a2));
  } else {
    if (role < 3) {
      const unsigned short* mp = msg + (size_t)beg * 384 + 192 + (role - 1) * 64 + ln;
      int i = beg;
      for (; i + 8 <= end; i += 8, mp += 3072) {
        float4 mt[8]; unsigned short v[8];
        #pragma unroll
        for (int u = 0; u < 8; ++u) { mt[u] = meta[i + u]; v[u] = mp[u * 384]; }
        #pragma unroll
        for (int u = 0; u < 8; ++u) {
          const float m = bf2f(v[u]);
          a0 = fmaf(m, mt[u].y, a0);
          a1 = fmaf(m, mt[u].z, a1);
          a2 = fmaf(m, mt[u].w, a2);
        }
      }
      for (; i < end; ++i, mp += 384) {
        const float4 mt = meta[i];
        const float m = bf2f(mp[0]);
        a0 = fmaf(m, mt.y, a0); a1 = fmaf(m, mt.z, a1); a2 = fmaf(m, mt.w, a2);
      }
    } else {
      const unsigned short* mp = msg + (size_t)beg * 384 + 320 + ln;
      int i = beg;
      for (; i + 8 <= end; i += 8, mp += 3072) {
        float4 mt[8]; unsigned short v[8];
        #pragma unroll
        for (int u = 0; u < 8; ++u) { mt[u] = meta[i + u]; v[u] = mp[u * 384]; }
        unsigned short x0[8], x1[8], x2[8];
        #pragma unroll
        for (int u = 0; u < 8; ++u) {
          const size_t base = (size_t)__float_as_int(mt[u].x) * NV + ln;
          x0[u] = xv16[base]; x1[u] = xv16[VPLANE + base]; x2[u] = xv16[2 * VPLANE + base];
        }
        #pragma unroll
        for (int u = 0; u < 8; ++u) {
          const float m = bf2f(v[u]);
          a0 = fmaf(m, bf2f(x0[u]), a0);
          a1 = fmaf(m, bf2f(x1[u]), a1);
          a2 = fmaf(m, bf2f(x2[u]), a2);
        }
      }
      for (; i < end; ++i, mp += 384) {
        const float4 mt = meta[i];
        const float m = bf2f(mp[0]);
        const size_t base = (size_t)__float_as_int(mt.x) * NV + ln;
        a0 = fmaf(m, bf2f(xv16[base]), a0);
        a1 = fmaf(m, bf2f(xv16[VPLANE + base]), a1);
        a2 = fmaf(m, bf2f(xv16[2 * VPLANE + base]), a2);
      }
    }
    const float nrm = sqrtf(fmaf(a0, a0, fmaf(a1, a1, a2 * a2)) + 1e-12f);
    const float sg = 1.f / (1.f + __expf(-nrm));
    const int u = (role < 3) ? (role - 1) * 64 + ln : 128 + ln;
    gv16[(size_t)0 * GVPLANE + (size_t)n * 192 + u] = bf16b(a0 * sg);
    gv16[(size_t)1 * GVPLANE + (size_t)n * 192 + u] = bf16b(a1 * sg);
    gv16[(size_t)2 * GVPLANE + (size_t)n * 192 + u] = bf16b(a2 * sg);
  }
}

// ===== node_post_mfma: 32 nodes/block, p_s/p_v GEMMs via MFMA + residual =======
__global__ __launch_bounds__(256) void node_post_mfma(
    const unsigned short* __restrict__ gs16, const unsigned short* __restrict__ gv16,
    const unsigned short* __restrict__ WqsP, const unsigned short* __restrict__ WqvP,
    const float* __restrict__ x_s, const float* __restrict__ x_v,
    float* __restrict__ out) {
  __shared__ __align__(16) unsigned short gsA[32 * 200];
  __shared__ __align__(16) unsigned short gvA[3][32 * 200];
  const int n0 = blockIdx.x * 32;
  const int t = threadIdx.x;
  const int lane = t & 63;
  const int w = t >> 6;
  const int l15 = lane & 15;
  const int l4 = lane >> 4;
  const float SC = 0.07216878364870323f;

  {
    const unsigned short* sp = gs16 + (size_t)n0 * 192;
    for (int idx = t; idx < 768; idx += 256) {
      const int row = idx / 24, ch = idx - row * 24;
      *(u16x8*)&gsA[row * 200 + ch * 8] = *(const u16x8*)&sp[row * 192 + ch * 8];
    }
    #pragma unroll
    for (int c = 0; c < 3; ++c) {
      const unsigned short* vp = gv16 + (size_t)c * GVPLANE + (size_t)n0 * 192;
      for (int idx = t; idx < 768; idx += 256) {
        const int row = idx / 24, ch = idx - row * 24;
        *(u16x8*)&gvA[c][row * 200 + ch * 8] = *(const u16x8*)&vp[row * 192 + ch * 8];
      }
    }
  }
  __syncthreads();

  f32x4 accS[2][2];
  f32x4 accV[3][2];
  #pragma unroll
  for (int j = 0; j < 2; ++j)
    #pragma unroll
    for (int mt = 0; mt < 2; ++mt) accS[j][mt] = (f32x4){0.f, 0.f, 0.f, 0.f};
  #pragma unroll
  for (int c = 0; c < 3; ++c)
    #pragma unroll
    for (int mt = 0; mt < 2; ++mt) accV[c][mt] = (f32x4){0.f, 0.f, 0.f, 0.f};

  #pragma unroll
  for (int kc = 0; kc < 6; ++kc) {
    bf16x8 aS[2], aV[3][2];
    #pragma unroll
    for (int mt = 0; mt < 2; ++mt)
      aS[mt] = *(const bf16x8*)&gsA[(mt * 16 + l15) * 200 + kc * 32 + l4 * 8];
    #pragma unroll
    for (int c = 0; c < 3; ++c)
      #pragma unroll
      for (int mt = 0; mt < 2; ++mt)
        aV[c][mt] = *(const bf16x8*)&gvA[c][(mt * 16 + l15) * 200 + kc * 32 + l4 * 8];
    const bf16x8 bS0 = *(const bf16x8*)&WqsP[(((size_t)(w * 2 + 0) * 6 + kc) * 64 + lane) * 8];
    const bf16x8 bS1 = *(const bf16x8*)&WqsP[(((size_t)(w * 2 + 1) * 6 + kc) * 64 + lane) * 8];
    const bf16x8 bV  = *(const bf16x8*)&WqvP[(((size_t)w * 6 + kc) * 64 + lane) * 8];
    #pragma unroll
    for (int mt = 0; mt < 2; ++mt) {
      accS[0][mt] = __builtin_amdgcn_mfma_f32_16x16x32_bf16(aS[mt], bS0, accS[0][mt], 0, 0, 0);
      accS[1][mt] = __builtin_amdgcn_mfma_f32_16x16x32_bf16(aS[mt], bS1, accS[1][mt], 0, 0, 0);
    }
    #pragma unroll
    for (int c = 0; c < 3; ++c)
      #pragma unroll
      for (int mt = 0; mt < 2; ++mt)
        accV[c][mt] = __builtin_amdgcn_mfma_f32_16x16x32_bf16(aV[c][mt], bV, accV[c][mt], 0, 0, 0);
  }

  #pragma unroll
  for (int j = 0; j < 2; ++j) {
    const int col = (w * 2 + j) * 16 + l15;
    #pragma unroll
    for (int mt = 0; mt < 2; ++mt)
      #pragma unroll
      for (int i = 0; i < 4; ++i) {
        const int row = n0 + mt * 16 + l4 * 4 + i;
        out[(size_t)row * 320 + col] =
            x_s[(size_t)row * NS + col] + accS[j][mt][i] * SC;
      }
  }
  {
    const int vch = w * 16 + l15;
    #pragma unroll
    for (int mt = 0; mt < 2; ++mt)
      #pragma unroll
      for (int i = 0; i < 4; ++i) {
        const int row = n0 + mt * 16 + l4 * 4 + i;
        const float* xvp = x_v + (size_t)row * (NV * 3) + vch * 3;
        float o0 = xvp[0] + accV[0][mt][i] * SC;
        float o1 = xvp[1] + accV[1][mt][i] * SC;
        float o2 = xvp[2] + accV[2][mt][i] * SC;
        float* op = out + (size_t)row * 320 + NS + vch * 3;
        op[0] = o0; op[1] = o1; op[2] = o2;
      }
  }
}

extern "C" void kernel_launch(void* const* d_in, const int* in_sizes, int n_in,
                              void* d_out, int out_size, void* d_ws, size_t ws_size,
                              hipStream_t stream) {
  const float* node_feat = (const float*)d_in[0];
  const float* edge_attr = (const float*)d_in[1];
  const float* edge_rshs = (const float*)d_in[2];
  const int*   edge_index = (const int*)d_in[3];
  const float* Wps = (const float*)d_in[4];
  const float* bps = (const float*)d_in[5];
  const float* Wpv = (const float*)d_in[6];
  const float* W1  = (const float*)d_in[7];
  const float* b1  = (const float*)d_in[8];
  const float* W2  = (const float*)d_in[9];
  const float* b2  = (const float*)d_in[10];
  const float* Wqs = (const float*)d_in[11];
  const float* Wqv = (const float*)d_in[12];
  float* out = (float*)d_out;

  float* x_s = (float*)d_ws;                                            // 16000*128 f32
  float* x_v = x_s + (size_t)NNODE * NS;                                // 16000*192 f32
  unsigned short* msg = (unsigned short*)(x_v + (size_t)NNODE * NV * 3);// 256000*384 bf16
  unsigned short* W1P = msg + (size_t)NEDGE * 384;                      // 4096
  unsigned short* W2P = W1P + 8 * 64 * 8;                               // 49152
  unsigned short* WqsP = W2P + 24 * 4 * 64 * 8;                         // 24576
  unsigned short* WqvP = WqsP + 8 * 6 * 64 * 8;                         // 12288
  unsigned short* x_s16 = WqvP + 4 * 6 * 64 * 8;                        // 2,048,000
  unsigned short* xv16 = x_s16 + (size_t)NNODE * NS;                    // 3,072,000
  unsigned short* gs16 = xv16 + (size_t)3 * VPLANE;                     // 3,072,000
  unsigned short* gv16 = gs16 + (size_t)NNODE * 192;                    // 9,216,000
  float4* meta = (float4*)(gv16 + (size_t)3 * GVPLANE);                 // NEDGE float4
  int* row_start = (int*)(meta + NEDGE);                                // NNODE+1
  int* cursor = row_start + (NNODE + 1);                                // NNODE
  int* perm = cursor + NNODE;                                           // NEDGE

  pack_weights<<<192, 256, 0, stream>>>(W1, W2, Wqs, Wqv, W1P, W2P, WqsP, WqvP,
      cursor);
  node_pre4<<<NNODE / 4, 256, 0, stream>>>(node_feat, Wps, bps, Wpv, x_s, x_v,
      x_s16, xv16);
  hist_kernel<<<(NEDGE + 255) / 256, 256, 0, stream>>>(edge_index, cursor);
  scan_kernel<<<1, 256, 0, stream>>>(cursor, row_start, cursor);
  scatter_kernel<<<(NEDGE + 255) / 256, 256, 0, stream>>>(edge_index, edge_rshs,
      cursor, perm, meta);
  edge_mlp_mfma<<<NEDGE / EPB, 256, 0, stream>>>(edge_attr, edge_rshs, edge_index,
      perm, W1P, b1, W2P, b2, x_s16, xv16, msg);
  node_gather<<<NNODE, 256, 0, stream>>>(msg, row_start, meta, xv16, gs16, gv16);
  node_post_mfma<<<NNODE / 32, 256, 0, stream>>>(gs16, gv16, WqsP, WqvP,
      x_s, x_v, out);
}

// Round 14
// 276.356 us; speedup vs baseline: 1.0481x; 1.0481x over previous
//
#include <hip/hip_runtime.h>
#include <hip/hip_bf16.h>

#define NS 128
#define NV 64
#define TPC 192
#define NBASIS 16
#define HID 128
#define WOUT 384
#define NNODE 16000
#define NEDGE 256000
#define EPB 32
#define GVPLANE 3072000   // 16000*192
#define VPLANE  1024000   // 16000*64

typedef __attribute__((ext_vector_type(8))) short bf16x8;
typedef __attribute__((ext_vector_type(8))) unsigned short u16x8;
typedef __attribute__((ext_vector_type(4))) unsigned short u16x4;
typedef __attribute__((ext_vector_type(4))) float f32x4;

__device__ __forceinline__ float silu_f(float x) { return x / (1.0f + __expf(-x)); }
__device__ __forceinline__ unsigned short bf16b(float x) {
  __hip_bfloat16 h = __float2bfloat16(x);
  return *reinterpret_cast<unsigned short*>(&h);
}
__device__ __forceinline__ float bf2f(unsigned short u) {
  return __uint_as_float(((unsigned)u) << 16);
}

// ------- pack W1/W2/Wqs/Wqv into MFMA B-fragment order (bf16); zero cursor ----
__global__ __launch_bounds__(256) void pack_weights(
    const float* __restrict__ W1, const float* __restrict__ W2,
    const float* __restrict__ Wqs, const float* __restrict__ Wqv,
    unsigned short* __restrict__ W1P, unsigned short* __restrict__ W2P,
    unsigned short* __restrict__ WqsP, unsigned short* __restrict__ WqvP,
    int* __restrict__ cursor) {
  const int id = blockIdx.x * 256 + threadIdx.x;
  const int j = id & 7, lane = (id >> 3) & 63;
  const int kj = (lane >> 4) * 8 + j;       // k-offset within 32-chunk
  const int nc = lane & 15;                 // col within 16-tile
  if (id < NNODE) cursor[id] = 0;           // replaces hipMemsetAsync
  if (id < 24 * 4 * 64 * 8) {               // W2P[nt24][kc4][lane][8]
    const int kc = (id >> 9) & 3, nt = id >> 11;
    W2P[id] = bf16b(W2[(kc * 32 + kj) * WOUT + nt * 16 + nc]);
  }
  if (id < 8 * 64 * 8) {                    // W1P[nt8][lane][8] (K=16 padded to 32)
    const int nt = id >> 9;
    W1P[id] = (kj < NBASIS) ? bf16b(W1[kj * HID + nt * 16 + nc]) : (unsigned short)0;
  }
  if (id < 8 * 6 * 64 * 8) {                // WqsP[nt8][kc6][lane][8]
    const int kc = (id >> 9) % 6, nt = id / (6 * 512);
    WqsP[id] = bf16b(Wqs[(kc * 32 + kj) * NS + nt * 16 + nc]);
  }
  if (id < 4 * 6 * 64 * 8) {                // WqvP[nt4][kc6][lane][8]
    const int kc = (id >> 9) % 6, nt = id / (6 * 512);
    WqvP[id] = bf16b(Wqv[(kc * 32 + kj) * NV + nt * 16 + nc]);
  }
}

// -------- node_pre: 4 nodes/block; also emits bf16 x_s16 and xv16 planes ------
__global__ __launch_bounds__(256) void node_pre4(
    const float* __restrict__ node_feat, const float* __restrict__ Wps,
    const float* __restrict__ bps, const float* __restrict__ Wpv,
    float* __restrict__ x_s, float* __restrict__ x_v,
    unsigned short* __restrict__ x_s16, unsigned short* __restrict__ xv16) {
  const int n0 = blockIdx.x * 4;
  const int t = threadIdx.x;
  __shared__ float s_sh[4][NS];
  __shared__ float v_sh[4][NV * 3];
  for (int i = t; i < 4 * 320; i += 256) {
    const int nn = i / 320, off = i - nn * 320;
    const float val = node_feat[(size_t)(n0 + nn) * 320 + off];
    if (off < NS) s_sh[nn][off] = val; else v_sh[nn][off - NS] = val;
  }
  __syncthreads();
  for (int o = t; o < 320; o += 256) {
    if (o < NS) {
      float a0 = 0.f, a1 = 0.f, a2 = 0.f, a3 = 0.f;
      #pragma unroll 8
      for (int u = 0; u < NS; ++u) {
        const float wv = Wps[u * NS + o];
        a0 = fmaf(s_sh[0][u], wv, a0); a1 = fmaf(s_sh[1][u], wv, a1);
        a2 = fmaf(s_sh[2][u], wv, a2); a3 = fmaf(s_sh[3][u], wv, a3);
      }
      const float b = bps[o];
      const float r0 = a0 * 0.08838834764831845f + b;
      const float r1 = a1 * 0.08838834764831845f + b;
      const float r2 = a2 * 0.08838834764831845f + b;
      const float r3 = a3 * 0.08838834764831845f + b;
      x_s[(size_t)(n0 + 0) * NS + o] = r0; x_s16[(size_t)(n0 + 0) * NS + o] = bf16b(r0);
      x_s[(size_t)(n0 + 1) * NS + o] = r1; x_s16[(size_t)(n0 + 1) * NS + o] = bf16b(r1);
      x_s[(size_t)(n0 + 2) * NS + o] = r2; x_s16[(size_t)(n0 + 2) * NS + o] = bf16b(r2);
      x_s[(size_t)(n0 + 3) * NS + o] = r3; x_s16[(size_t)(n0 + 3) * NS + o] = bf16b(r3);
    } else {
      const int q = o - NS;
      const int vch = q / 3, c = q - vch * 3;
      float a0 = 0.f, a1 = 0.f, a2 = 0.f, a3 = 0.f;
      #pragma unroll 8
      for (int u = 0; u < NV; ++u) {
        const float wv = Wpv[u * NV + vch];
        a0 = fmaf(v_sh[0][u * 3 + c], wv, a0); a1 = fmaf(v_sh[1][u * 3 + c], wv, a1);
        a2 = fmaf(v_sh[2][u * 3 + c], wv, a2); a3 = fmaf(v_sh[3][u * 3 + c], wv, a3);
      }
      const float r0 = a0 * 0.125f, r1 = a1 * 0.125f, r2 = a2 * 0.125f, r3 = a3 * 0.125f;
      x_v[(size_t)(n0 + 0) * (NV * 3) + q] = r0;
      x_v[(size_t)(n0 + 1) * (NV * 3) + q] = r1;
      x_v[(size_t)(n0 + 2) * (NV * 3) + q] = r2;
      x_v[(size_t)(n0 + 3) * (NV * 3) + q] = r3;
      unsigned short* pl = xv16 + (size_t)c * VPLANE;
      pl[(size_t)(n0 + 0) * NV + vch] = bf16b(r0);
      pl[(size_t)(n0 + 1) * NV + vch] = bf16b(r1);
      pl[(size_t)(n0 + 2) * NV + vch] = bf16b(r2);
      pl[(size_t)(n0 + 3) * NV + vch] = bf16b(r3);
    }
  }
}

// ================= CSR build =================
__global__ void hist_kernel(const int* __restrict__ ei, int* __restrict__ cnt) {
  int e = blockIdx.x * 256 + threadIdx.x;
  if (e < NEDGE) atomicAdd(&cnt[ei[e]], 1);
}

__global__ __launch_bounds__(256) void scan_kernel(
    const int* __restrict__ cnt, int* __restrict__ row_start, int* __restrict__ cursor) {
  __shared__ int part[256];
  const int t = threadIdx.x;
  const int base = t * 63;
  int s = 0;
  for (int i = 0; i < 63; ++i) {
    int idx = base + i;
    if (idx < NNODE) s += cnt[idx];
  }
  part[t] = s;
  __syncthreads();
  if (t == 0) {
    int run = 0;
    for (int i = 0; i < 256; ++i) { int x = part[i]; part[i] = run; run += x; }
  }
  __syncthreads();
  int run = part[t];
  for (int i = 0; i < 63; ++i) {
    int idx = base + i;
    if (idx < NNODE) {
      int c = cnt[idx];   // read before overwrite (cnt aliases cursor)
      row_start[idx] = run;
      cursor[idx] = run;
      run += c;
    }
  }
  if (t == 255) row_start[NNODE] = run;
}

__global__ void scatter_kernel(const int* __restrict__ ei,
                               const float* __restrict__ edge_rshs,
                               int* __restrict__ cursor, int* __restrict__ perm,
                               float4* __restrict__ meta) {
  int e = blockIdx.x * 256 + threadIdx.x;
  if (e < NEDGE) {
    int p = atomicAdd(&cursor[ei[e]], 1);
    perm[e] = p;
    float4 m;
    m.x = __int_as_float(ei[NEDGE + e]);
    m.y = edge_rshs[e * 4 + 1];
    m.z = edge_rshs[e * 4 + 2];
    m.w = edge_rshs[e * 4 + 3];
    meta[p] = m;
  }
}

// ================= edge MLP via MFMA -> bf16 messages at CSR slots ============
// (R12 structure: union SMU, b1/b2 in LDS, unrolled phase 3, bias-init accs)
__global__ __launch_bounds__(256) void edge_mlp_mfma(
    const float* __restrict__ edge_attr, const float* __restrict__ edge_rshs,
    const int* __restrict__ edge_index, const int* __restrict__ perm,
    const unsigned short* __restrict__ W1P, const float* __restrict__ b1,
    const unsigned short* __restrict__ W2P, const float* __restrict__ b2,
    const unsigned short* __restrict__ x_s16, const unsigned short* __restrict__ xv16,
    unsigned short* __restrict__ msg) {
  union SMU {
    struct { unsigned short ea[32 * 48]; unsigned short Hs[32 * 136]; } p1;
    unsigned short msgb[32 * 392];
  };
  __shared__ __align__(16) SMU sm;
  __shared__ __align__(16) unsigned short sj[32][136];
  __shared__ __align__(16) unsigned short vd[32][72];
  __shared__ unsigned short b2s[384];
  __shared__ unsigned short b1s[128];
  __shared__ int src_sh[32];
  __shared__ int slot_sh[32];
  __shared__ float rsh_sh[32][4];
  const int t = threadIdx.x;
  const int lane = t & 63;
  const int w = t >> 6;
  const int l15 = lane & 15;
  const int l4 = lane >> 4;
  const int eblk = blockIdx.x * EPB;

  // ---- phase 0: metadata + bias staging + vectorized ea staging
  if (t < 32 * 4) rsh_sh[t >> 2][t & 3] = edge_rshs[(size_t)eblk * 4 + t];
  if (t < 32) {
    src_sh[t] = edge_index[NEDGE + eblk + t];
    slot_sh[t] = perm[eblk + t];
  }
  for (int i = t; i < 384; i += 256) b2s[i] = bf16b(b2[i]);
  if (t < 128) b1s[t] = bf16b(b1[t]);
  if (t < 128) {
    const int e = t >> 2, q = t & 3;
    const float4 v = *(const float4*)&edge_attr[(size_t)(eblk + e) * NBASIS + q * 4];
    u16x4 tmp;
    tmp[0] = bf16b(v.x); tmp[1] = bf16b(v.y); tmp[2] = bf16b(v.z); tmp[3] = bf16b(v.w);
    *(u16x4*)&sm.p1.ea[e * 48 + q * 4] = tmp;
  } else {
    const int idx = t - 128;           // 128 chunks × 8 shorts of K-pad
    const int e = idx >> 2, q = idx & 3;
    *(u16x8*)&sm.p1.ea[e * 48 + 16 + q * 8] = (u16x8){0, 0, 0, 0, 0, 0, 0, 0};
  }
  __syncthreads();

  // ---- phase 1: GEMM1 (H = silu(ea@W1+b1)) + sj/vd staging from bf16 sources
  {
    const int mt = w & 1, ch = w >> 1;
    const bf16x8 afrag = *(const bf16x8*)&sm.p1.ea[(mt * 16 + l15) * 48 + l4 * 8];
    #pragma unroll
    for (int nt = 0; nt < 4; ++nt) {
      const int ntg = ch * 4 + nt;
      const bf16x8 bfrag = *(const bf16x8*)&W1P[((size_t)ntg * 64 + lane) * 8];
      const int col = ntg * 16 + l15;
      const float bias = bf2f(b1s[col]);
      f32x4 d = {bias, bias, bias, bias};   // bias folded into acc init
      d = __builtin_amdgcn_mfma_f32_16x16x32_bf16(afrag, bfrag, d, 0, 0, 0);
      #pragma unroll
      for (int i = 0; i < 4; ++i) {
        const int e = mt * 16 + l4 * 4 + i;
        sm.p1.Hs[e * 136 + col] = bf16b(silu_f(d[i]));
      }
    }
  }
  // sj: straight u16x8 copy from x_s16 (no conversions)
  #pragma unroll
  for (int p = 0; p < 2; ++p) {
    const int idx = p * 256 + t;
    const int e = idx >> 4, c8 = idx & 15;
    *(u16x8*)&sj[e][c8 * 8] =
        *(const u16x8*)&x_s16[(size_t)src_sh[e] * NS + c8 * 8];
  }
  // vd[e][u] = <v_j[u], r1> * inv_sqrt3 from bf16 planes
  #pragma unroll
  for (int p = 0; p < 8; ++p) {
    const int idx = p * 256 + t;
    const int e = idx >> 6, u = idx & 63;
    const size_t base = (size_t)src_sh[e] * NV + u;
    const float v0 = bf2f(xv16[base]);
    const float v1 = bf2f(xv16[VPLANE + base]);
    const float v2 = bf2f(xv16[2 * VPLANE + base]);
    const float dotv = fmaf(v0, rsh_sh[e][1], fmaf(v1, rsh_sh[e][2], v2 * rsh_sh[e][3]));
    vd[e][u] = bf16b(dotv * 0.5773502691896258f);
  }
  __syncthreads();

  // ---- phase 2: preload A-frags from Hs (then Hs is dead)
  bf16x8 afr[2][4];
  #pragma unroll
  for (int mt = 0; mt < 2; ++mt)
    #pragma unroll
    for (int k = 0; k < 4; ++k)
      afr[mt][k] = *(const bf16x8*)&sm.p1.Hs[(mt * 16 + l15) * 136 + k * 32 + l4 * 8];

  float r0a[2][4];
  #pragma unroll
  for (int mt = 0; mt < 2; ++mt)
    #pragma unroll
    for (int i = 0; i < 4; ++i) r0a[mt][i] = rsh_sh[mt * 16 + l4 * 4 + i][0];
  __syncthreads();   // everyone done reading Hs; msgb region now writable

  // ---- phase 3: GEMM2 + in-LDS epilogue, unrolled; bias folded into acc init
  #pragma unroll
  for (int nn = 0; nn < 6; ++nn) {
    const int nt = w * 6 + nn;
    bf16x8 bfr[4];
    #pragma unroll
    for (int k = 0; k < 4; ++k)
      bfr[k] = *(const bf16x8*)&W2P[(((size_t)nt * 4 + k) * 64 + lane) * 8];
    const int col = nt * 16 + l15;
    const float bias = bf2f(b2s[col]);
    f32x4 acc0 = {bias, bias, bias, bias}, acc1 = {bias, bias, bias, bias};
    #pragma unroll
    for (int k = 0; k < 4; ++k) {
      acc0 = __builtin_amdgcn_mfma_f32_16x16x32_bf16(afr[0][k], bfr[k], acc0, 0, 0, 0);
      acc1 = __builtin_amdgcn_mfma_f32_16x16x32_bf16(afr[1][k], bfr[k], acc1, 0, 0, 0);
    }
    if (col < NS) {
      #pragma unroll
      for (int mt = 0; mt < 2; ++mt)
        #pragma unroll
        for (int i = 0; i < 4; ++i) {
          const int e = mt * 16 + l4 * 4 + i;
          const float wv = mt ? acc1[i] : acc0[i];
          sm.msgb[e * 392 + col] = bf16b(wv * bf2f(sj[e][col]) * r0a[mt][i]);
        }
    } else if (col < NS + NV) {
      const int u = col - NS;
      #pragma unroll
      for (int mt = 0; mt < 2; ++mt)
        #pragma unroll
        for (int i = 0; i < 4; ++i) {
          const int e = mt * 16 + l4 * 4 + i;
          const float wv = mt ? acc1[i] : acc0[i];
          sm.msgb[e * 392 + col] = bf16b(wv * bf2f(vd[e][u]));
        }
    } else if (col < 2 * NS + NV) {
      const int sjc = col - (NS + NV);
      #pragma unroll
      for (int mt = 0; mt < 2; ++mt)
        #pragma unroll
        for (int i = 0; i < 4; ++i) {
          const int e = mt * 16 + l4 * 4 + i;
          const float wv = mt ? acc1[i] : acc0[i];
          sm.msgb[e * 392 + col] = bf16b(wv * bf2f(sj[e][sjc]));
        }
    } else {
      #pragma unroll
      for (int mt = 0; mt < 2; ++mt)
        #pragma unroll
        for (int i = 0; i < 4; ++i) {
          const int e = mt * 16 + l4 * 4 + i;
          const float wv = mt ? acc1[i] : acc0[i];
          sm.msgb[e * 392 + col] = bf16b(wv * r0a[mt][i]);
        }
    }
  }
  __syncthreads();

  // ---- phase 4: coalesced write-out, 768 B per edge row at its CSR slot
  #pragma unroll
  for (int p = 0; p < 6; ++p) {
    const int idx = p * 256 + t;
    const int e = idx / 48, c = idx - e * 48;
    const u16x8 vv = *(const u16x8*)&sm.msgb[e * 392 + c * 8];
    *(u16x8*)&msg[(size_t)slot_sh[e] * 384 + c * 8] = vv;
  }
}

// ===== node_gather: 4 role-waves, batch-8 unrolled loads ======================
// role 0: cols {2ln, 2ln+1} (one dword) + {128+ln}
// role 1/2: kind1 rows u=(role-1)*64+ln  (FMA with r1)
// role 3:   kind2 rows u=128+ln          (FMA with xv16 planes)
__global__ __launch_bounds__(256) void node_gather(
    const unsigned short* __restrict__ msg, const int* __restrict__ row_start,
    const float4* __restrict__ meta, const unsigned short* __restrict__ xv16,
    unsigned short* __restrict__ gs16, unsigned short* __restrict__ gv16) {
  const int n = blockIdx.x;
  const int t = threadIdx.x;
  const int role = t >> 6, ln = t & 63;
  const int beg = row_start[n], end = row_start[n + 1];

  float a0 = 0.f, a1 = 0.f, a2 = 0.f;

  if (role == 0) {
    const unsigned short* mp = msg + (size_t)beg * 384;
    int i = beg;
    for (; i + 8 <= end; i += 8, mp += 3072) {
      unsigned int pr[8]; unsigned short v2[8];
      #pragma unroll
      for (int u = 0; u < 8; ++u) {
        pr[u] = *(const unsigned int*)(mp + u * 384 + 2 * ln);
        v2[u] = mp[u * 384 + 128 + ln];
      }
      #pragma unroll
      for (int u = 0; u < 8; ++u) {
        a0 += __uint_as_float(pr[u] << 16);
        a1 += __uint_as_float(pr[u] & 0xffff0000u);
        a2 += bf2f(v2[u]);
      }
    }
    for (; i < end; ++i, mp += 384) {
      const unsigned int p = *(const unsigned int*)(mp + 2 * ln);
      a0 += __uint_as_float(p << 16);
      a1 += __uint_as_float(p & 0xffff0000u);
      a2 += bf2f(mp[128 + ln]);
    }
    gs16[(size_t)n * 192 + 2 * ln]     = bf16b(silu_f(a0));
    gs16[(size_t)n * 192 + 2 * ln + 1] = bf16b(silu_f(a1));
    gs16[(size_t)n * 192 + 128 + ln]   = bf16b(silu_f(a2));
  } else {
    if (role < 3) {
      const unsigned short* mp = msg + (size_t)beg * 384 + 192 + (role - 1) * 64 + ln;
      int i = beg;
      for (; i + 8 <= end; i += 8, mp += 3072) {
        float4 mt[8]; unsigned short v[8];
        #pragma unroll
        for (int u = 0; u < 8; ++u) { mt[u] = meta[i + u]; v[u] = mp[u * 384]; }
        #pragma unroll
        for (int u = 0; u < 8; ++u) {
          const float m = bf2f(v[u]);
          a0 = fmaf(m, mt[u].y, a0);
          a1 = fmaf(m, mt[u].z, a1);
          a2 = fmaf(m, mt[u].w, a2);
        }
      }
      for (; i < end; ++i, mp += 384) {
        const float4 mt = meta[i];
        const float m = bf2f(mp[0]);
        a0 = fmaf(m, mt.y, a0); a1 = fmaf(m, mt.z, a1); a2 = fmaf(m, mt.w, a2);
      }
    } else {
      const unsigned short* mp = msg + (size_t)beg * 384 + 320 + ln;
      int i = beg;
      for (; i + 8 <= end; i += 8, mp += 3072) {
        float4 mt[8]; unsigned short v[8];
        #pragma unroll
        for (int u = 0; u < 8; ++u) { mt[u] = meta[i + u]; v[u] = mp[u * 384]; }
        unsigned short x0[8], x1[8], x2[8];
        #pragma unroll
        for (int u = 0; u < 8; ++u) {
          const size_t base = (size_t)__float_as_int(mt[u].x) * NV + ln;
          x0[u] = xv16[base]; x1[u] = xv16[VPLANE + base]; x2[u] = xv16[2 * VPLANE + base];
        }
        #pragma unroll
        for (int u = 0; u < 8; ++u) {
          const float m = bf2f(v[u]);
          a0 = fmaf(m, bf2f(x0[u]), a0);
          a1 = fmaf(m, bf2f(x1[u]), a1);
          a2 = fmaf(m, bf2f(x2[u]), a2);
        }
      }
      for (; i < end; ++i, mp += 384) {
        const float4 mt = meta[i];
        const float m = bf2f(mp[0]);
        const size_t base = (size_t)__float_as_int(mt.x) * NV + ln;
        a0 = fmaf(m, bf2f(xv16[base]), a0);
        a1 = fmaf(m, bf2f(xv16[VPLANE + base]), a1);
        a2 = fmaf(m, bf2f(xv16[2 * VPLANE + base]), a2);
      }
    }
    const float nrm = sqrtf(fmaf(a0, a0, fmaf(a1, a1, a2 * a2)) + 1e-12f);
    const float sg = 1.f / (1.f + __expf(-nrm));
    const int u = (role < 3) ? (role - 1) * 64 + ln : 128 + ln;
    gv16[(size_t)0 * GVPLANE + (size_t)n * 192 + u] = bf16b(a0 * sg);
    gv16[(size_t)1 * GVPLANE + (size_t)n * 192 + u] = bf16b(a1 * sg);
    gv16[(size_t)2 * GVPLANE + (size_t)n * 192 + u] = bf16b(a2 * sg);
  }
}

// ===== node_post_mfma: 32 nodes/block, p_s/p_v GEMMs via MFMA + residual =======
__global__ __launch_bounds__(256) void node_post_mfma(
    const unsigned short* __restrict__ gs16, const unsigned short* __restrict__ gv16,
    const unsigned short* __restrict__ WqsP, const unsigned short* __restrict__ WqvP,
    const float* __restrict__ x_s, const float* __restrict__ x_v,
    float* __restrict__ out) {
  __shared__ __align__(16) unsigned short gsA[32 * 200];
  __shared__ __align__(16) unsigned short gvA[3][32 * 200];
  const int n0 = blockIdx.x * 32;
  const int t = threadIdx.x;
  const int lane = t & 63;
  const int w = t >> 6;
  const int l15 = lane & 15;
  const int l4 = lane >> 4;
  const float SC = 0.07216878364870323f;

  {
    const unsigned short* sp = gs16 + (size_t)n0 * 192;
    for (int idx = t; idx < 768; idx += 256) {
      const int row = idx / 24, ch = idx - row * 24;
      *(u16x8*)&gsA[row * 200 + ch * 8] = *(const u16x8*)&sp[row * 192 + ch * 8];
    }
    #pragma unroll
    for (int c = 0; c < 3; ++c) {
      const unsigned short* vp = gv16 + (size_t)c * GVPLANE + (size_t)n0 * 192;
      for (int idx = t; idx < 768; idx += 256) {
        const int row = idx / 24, ch = idx - row * 24;
        *(u16x8*)&gvA[c][row * 200 + ch * 8] = *(const u16x8*)&vp[row * 192 + ch * 8];
      }
    }
  }
  __syncthreads();

  f32x4 accS[2][2];
  f32x4 accV[3][2];
  #pragma unroll
  for (int j = 0; j < 2; ++j)
    #pragma unroll
    for (int mt = 0; mt < 2; ++mt) accS[j][mt] = (f32x4){0.f, 0.f, 0.f, 0.f};
  #pragma unroll
  for (int c = 0; c < 3; ++c)
    #pragma unroll
    for (int mt = 0; mt < 2; ++mt) accV[c][mt] = (f32x4){0.f, 0.f, 0.f, 0.f};

  #pragma unroll
  for (int kc = 0; kc < 6; ++kc) {
    bf16x8 aS[2], aV[3][2];
    #pragma unroll
    for (int mt = 0; mt < 2; ++mt)
      aS[mt] = *(const bf16x8*)&gsA[(mt * 16 + l15) * 200 + kc * 32 + l4 * 8];
    #pragma unroll
    for (int c = 0; c < 3; ++c)
      #pragma unroll
      for (int mt = 0; mt < 2; ++mt)
        aV[c][mt] = *(const bf16x8*)&gvA[c][(mt * 16 + l15) * 200 + kc * 32 + l4 * 8];
    const bf16x8 bS0 = *(const bf16x8*)&WqsP[(((size_t)(w * 2 + 0) * 6 + kc) * 64 + lane) * 8];
    const bf16x8 bS1 = *(const bf16x8*)&WqsP[(((size_t)(w * 2 + 1) * 6 + kc) * 64 + lane) * 8];
    const bf16x8 bV  = *(const bf16x8*)&WqvP[(((size_t)w * 6 + kc) * 64 + lane) * 8];
    #pragma unroll
    for (int mt = 0; mt < 2; ++mt) {
      accS[0][mt] = __builtin_amdgcn_mfma_f32_16x16x32_bf16(aS[mt], bS0, accS[0][mt], 0, 0, 0);
      accS[1][mt] = __builtin_amdgcn_mfma_f32_16x16x32_bf16(aS[mt], bS1, accS[1][mt], 0, 0, 0);
    }
    #pragma unroll
    for (int c = 0; c < 3; ++c)
      #pragma unroll
      for (int mt = 0; mt < 2; ++mt)
        accV[c][mt] = __builtin_amdgcn_mfma_f32_16x16x32_bf16(aV[c][mt], bV, accV[c][mt], 0, 0, 0);
  }

  #pragma unroll
  for (int j = 0; j < 2; ++j) {
    const int col = (w * 2 + j) * 16 + l15;
    #pragma unroll
    for (int mt = 0; mt < 2; ++mt)
      #pragma unroll
      for (int i = 0; i < 4; ++i) {
        const int row = n0 + mt * 16 + l4 * 4 + i;
        out[(size_t)row * 320 + col] =
            x_s[(size_t)row * NS + col] + accS[j][mt][i] * SC;
      }
  }
  {
    const int vch = w * 16 + l15;
    #pragma unroll
    for (int mt = 0; mt < 2; ++mt)
      #pragma unroll
      for (int i = 0; i < 4; ++i) {
        const int row = n0 + mt * 16 + l4 * 4 + i;
        const float* xvp = x_v + (size_t)row * (NV * 3) + vch * 3;
        float o0 = xvp[0] + accV[0][mt][i] * SC;
        float o1 = xvp[1] + accV[1][mt][i] * SC;
        float o2 = xvp[2] + accV[2][mt][i] * SC;
        float* op = out + (size_t)row * 320 + NS + vch * 3;
        op[0] = o0; op[1] = o1; op[2] = o2;
      }
  }
}

extern "C" void kernel_launch(void* const* d_in, const int* in_sizes, int n_in,
                              void* d_out, int out_size, void* d_ws, size_t ws_size,
                              hipStream_t stream) {
  const float* node_feat = (const float*)d_in[0];
  const float* edge_attr = (const float*)d_in[1];
  const float* edge_rshs = (const float*)d_in[2];
  const int*   edge_index = (const int*)d_in[3];
  const float* Wps = (const float*)d_in[4];
  const float* bps = (const float*)d_in[5];
  const float* Wpv = (const float*)d_in[6];
  const float* W1  = (const float*)d_in[7];
  const float* b1  = (const float*)d_in[8];
  const float* W2  = (const float*)d_in[9];
  const float* b2  = (const float*)d_in[10];
  const float* Wqs = (const float*)d_in[11];
  const float* Wqv = (const float*)d_in[12];
  float* out = (float*)d_out;

  float* x_s = (float*)d_ws;                                            // 16000*128 f32
  float* x_v = x_s + (size_t)NNODE * NS;                                // 16000*192 f32
  unsigned short* msg = (unsigned short*)(x_v + (size_t)NNODE * NV * 3);// 256000*384 bf16
  unsigned short* W1P = msg + (size_t)NEDGE * 384;                      // 4096
  unsigned short* W2P = W1P + 8 * 64 * 8;                               // 49152
  unsigned short* WqsP = W2P + 24 * 4 * 64 * 8;                         // 24576
  unsigned short* WqvP = WqsP + 8 * 6 * 64 * 8;                         // 12288
  unsigned short* x_s16 = WqvP + 4 * 6 * 64 * 8;                        // 2,048,000
  unsigned short* xv16 = x_s16 + (size_t)NNODE * NS;                    // 3,072,000
  unsigned short* gs16 = xv16 + (size_t)3 * VPLANE;                     // 3,072,000
  unsigned short* gv16 = gs16 + (size_t)NNODE * 192;                    // 9,216,000
  float4* meta = (float4*)(gv16 + (size_t)3 * GVPLANE);                 // NEDGE float4
  int* row_start = (int*)(meta + NEDGE);                                // NNODE+1
  int* cursor = row_start + (NNODE + 1);                                // NNODE
  int* perm = cursor + NNODE;                                           // NEDGE

  pack_weights<<<192, 256, 0, stream>>>(W1, W2, Wqs, Wqv, W1P, W2P, WqsP, WqvP,
      cursor);
  node_pre4<<<NNODE / 4, 256, 0, stream>>>(node_feat, Wps, bps, Wpv, x_s, x_v,
      x_s16, xv16);
  hist_kernel<<<(NEDGE + 255) / 256, 256, 0, stream>>>(edge_index, cursor);
  scan_kernel<<<1, 256, 0, stream>>>(cursor, row_start, cursor);
  scatter_kernel<<<(NEDGE + 255) / 256, 256, 0, stream>>>(edge_index, edge_rshs,
      cursor, perm, meta);
  edge_mlp_mfma<<<NEDGE / EPB, 256, 0, stream>>>(edge_attr, edge_rshs, edge_index,
      perm, W1P, b1, W2P, b2, x_s16, xv16, msg);
  node_gather<<<NNODE, 256, 0, stream>>>(msg, row_start, meta, xv16, gs16, gv16);
  node_post_mfma<<<NNODE / 32, 256, 0, stream>>>(gs16, gv16, WqsP, WqvP,
      x_s, x_v, out);
}

// Round 15
// 252.104 us; speedup vs baseline: 1.1489x; 1.0962x over previous
//
#include <hip/hip_runtime.h>
#include <hip/hip_bf16.h>

#define NS 128
#define NV 64
#define TPC 192
#define NBASIS 16
#define HID 128
#define WOUT 384
#define NNODE 16000
#define NEDGE 256000
#define EPB 32
#define GVPLANE 3072000   // 16000*192
#define VPLANE  1024000   // 16000*64

typedef __attribute__((ext_vector_type(8))) short bf16x8;
typedef __attribute__((ext_vector_type(8))) unsigned short u16x8;
typedef __attribute__((ext_vector_type(4))) unsigned short u16x4;
typedef __attribute__((ext_vector_type(4))) float f32x4;

__device__ __forceinline__ float silu_f(float x) { return x / (1.0f + __expf(-x)); }
__device__ __forceinline__ unsigned short bf16b(float x) {
  __hip_bfloat16 h = __float2bfloat16(x);
  return *reinterpret_cast<unsigned short*>(&h);
}
__device__ __forceinline__ float bf2f(unsigned short u) {
  return __uint_as_float(((unsigned)u) << 16);
}

// ---- pack W1/W2/Wqs/Wqv/Wps/Wpv into MFMA B-fragment order (bf16, scales folded)
__global__ __launch_bounds__(256) void pack_weights(
    const float* __restrict__ W1, const float* __restrict__ W2,
    const float* __restrict__ Wqs, const float* __restrict__ Wqv,
    const float* __restrict__ Wps, const float* __restrict__ Wpv,
    unsigned short* __restrict__ W1P, unsigned short* __restrict__ W2P,
    unsigned short* __restrict__ WqsP, unsigned short* __restrict__ WqvP,
    unsigned short* __restrict__ WpsP, unsigned short* __restrict__ WpvP,
    int* __restrict__ cursor) {
  const int id = blockIdx.x * 256 + threadIdx.x;
  const int j = id & 7, lane = (id >> 3) & 63;
  const int kj = (lane >> 4) * 8 + j;       // k-offset within 32-chunk
  const int nc = lane & 15;                 // col within 16-tile
  const float SC = 0.07216878364870323f;
  if (id < NNODE) cursor[id] = 0;           // replaces hipMemsetAsync
  if (id < 24 * 4 * 64 * 8) {               // W2P[nt24][kc4][lane][8]
    const int kc = (id >> 9) & 3, nt = id >> 11;
    W2P[id] = bf16b(W2[(kc * 32 + kj) * WOUT + nt * 16 + nc]);
  }
  if (id < 8 * 64 * 8) {                    // W1P[nt8][lane][8] (K=16 padded to 32)
    const int nt = id >> 9;
    W1P[id] = (kj < NBASIS) ? bf16b(W1[kj * HID + nt * 16 + nc]) : (unsigned short)0;
  }
  if (id < 8 * 6 * 64 * 8) {                // WqsP[nt8][kc6][lane][8], SC folded
    const int kc = (id >> 9) % 6, nt = id / (6 * 512);
    WqsP[id] = bf16b(Wqs[(kc * 32 + kj) * NS + nt * 16 + nc] * SC);
  }
  if (id < 4 * 6 * 64 * 8) {                // WqvP[nt4][kc6][lane][8], SC folded
    const int kc = (id >> 9) % 6, nt = id / (6 * 512);
    WqvP[id] = bf16b(Wqv[(kc * 32 + kj) * NV + nt * 16 + nc] * SC);
  }
  if (id < 8 * 4 * 64 * 8) {                // WpsP[nt8][kc4][lane][8], 1/sqrt(128) folded
    const int kc = (id >> 9) & 3, nt = id >> 11;
    WpsP[id] = bf16b(Wps[(kc * 32 + kj) * NS + nt * 16 + nc] * 0.08838834764831845f);
  }
  if (id < 4 * 2 * 64 * 8) {                // WpvP[nt4][kc2][lane][8], 1/8 folded
    const int kc = (id >> 9) & 1, nt = id >> 10;
    WpvP[id] = bf16b(Wpv[(kc * 32 + kj) * NV + nt * 16 + nc] * 0.125f);
  }
}

// ====== node_pre_mfma: 32 nodes/block; x_s/x_v pre-GEMMs via MFMA =============
// Same fragment mapping as node_post_mfma (proven): A from LDS bf16 tiles,
// B from packed weights, C rows = mt*16+l4*4+i, col = nt*16+l15.
__global__ __launch_bounds__(256) void node_pre_mfma(
    const float* __restrict__ node_feat, const float* __restrict__ bps,
    const unsigned short* __restrict__ WpsP, const unsigned short* __restrict__ WpvP,
    float* __restrict__ x_s, float* __restrict__ x_v,
    unsigned short* __restrict__ x_s16, unsigned short* __restrict__ xv16) {
  __shared__ __align__(16) unsigned short as_[32 * 136];   // s-part rows, bf16
  __shared__ __align__(16) unsigned short avp[3][32 * 72]; // v planes by c, bf16
  const int n0 = blockIdx.x * 32;
  const int t = threadIdx.x;
  const int lane = t & 63;
  const int w = t >> 6;
  const int l15 = lane & 15;
  const int l4 = lane >> 4;

  // stage s-part (coalesced float4 -> bf16)
  #pragma unroll
  for (int p = 0; p < 4; ++p) {
    const int idx = p * 256 + t;
    const int r = idx >> 5, c4 = idx & 31;
    const float4 v = *(const float4*)&node_feat[(size_t)(n0 + r) * 320 + c4 * 4];
    u16x4 tmp;
    tmp[0] = bf16b(v.x); tmp[1] = bf16b(v.y); tmp[2] = bf16b(v.z); tmp[3] = bf16b(v.w);
    *(u16x4*)&as_[r * 136 + c4 * 4] = tmp;
  }
  // stage v-part into 3 c-planes
  #pragma unroll
  for (int p = 0; p < 8; ++p) {
    const int idx = p * 256 + t;
    const int r = idx >> 6, u = idx & 63;
    const float* vp = &node_feat[(size_t)(n0 + r) * 320 + 128 + u * 3];
    avp[0][r * 72 + u] = bf16b(vp[0]);
    avp[1][r * 72 + u] = bf16b(vp[1]);
    avp[2][r * 72 + u] = bf16b(vp[2]);
  }
  __syncthreads();

  // accS[j][mt]: x_s ntiles {2w, 2w+1}; bias bps folded into init
  f32x4 accS[2][2];
  #pragma unroll
  for (int jj = 0; jj < 2; ++jj) {
    const float b = bps[(w * 2 + jj) * 16 + l15];
    #pragma unroll
    for (int mt = 0; mt < 2; ++mt) accS[jj][mt] = (f32x4){b, b, b, b};
  }
  f32x4 accV[3][2];
  #pragma unroll
  for (int c = 0; c < 3; ++c)
    #pragma unroll
    for (int mt = 0; mt < 2; ++mt) accV[c][mt] = (f32x4){0.f, 0.f, 0.f, 0.f};

  #pragma unroll
  for (int kc = 0; kc < 4; ++kc) {
    bf16x8 aS[2];
    #pragma unroll
    for (int mt = 0; mt < 2; ++mt)
      aS[mt] = *(const bf16x8*)&as_[(mt * 16 + l15) * 136 + kc * 32 + l4 * 8];
    const bf16x8 bS0 = *(const bf16x8*)&WpsP[(((size_t)(w * 2 + 0) * 4 + kc) * 64 + lane) * 8];
    const bf16x8 bS1 = *(const bf16x8*)&WpsP[(((size_t)(w * 2 + 1) * 4 + kc) * 64 + lane) * 8];
    #pragma unroll
    for (int mt = 0; mt < 2; ++mt) {
      accS[0][mt] = __builtin_amdgcn_mfma_f32_16x16x32_bf16(aS[mt], bS0, accS[0][mt], 0, 0, 0);
      accS[1][mt] = __builtin_amdgcn_mfma_f32_16x16x32_bf16(aS[mt], bS1, accS[1][mt], 0, 0, 0);
    }
  }
  #pragma unroll
  for (int kc = 0; kc < 2; ++kc) {
    const bf16x8 bV = *(const bf16x8*)&WpvP[(((size_t)w * 2 + kc) * 64 + lane) * 8];
    #pragma unroll
    for (int c = 0; c < 3; ++c) {
      bf16x8 aV[2];
      #pragma unroll
      for (int mt = 0; mt < 2; ++mt)
        aV[mt] = *(const bf16x8*)&avp[c][(mt * 16 + l15) * 72 + kc * 32 + l4 * 8];
      #pragma unroll
      for (int mt = 0; mt < 2; ++mt)
        accV[c][mt] = __builtin_amdgcn_mfma_f32_16x16x32_bf16(aV[mt], bV, accV[c][mt], 0, 0, 0);
    }
  }

  // epilogue: x_s (f32 + bf16), x_v (f32 interleaved + bf16 planes)
  #pragma unroll
  for (int jj = 0; jj < 2; ++jj) {
    const int col = (w * 2 + jj) * 16 + l15;
    #pragma unroll
    for (int mt = 0; mt < 2; ++mt)
      #pragma unroll
      for (int i = 0; i < 4; ++i) {
        const int row = n0 + mt * 16 + l4 * 4 + i;
        const float r = accS[jj][mt][i];
        x_s[(size_t)row * NS + col] = r;
        x_s16[(size_t)row * NS + col] = bf16b(r);
      }
  }
  {
    const int vch = w * 16 + l15;
    #pragma unroll
    for (int mt = 0; mt < 2; ++mt)
      #pragma unroll
      for (int i = 0; i < 4; ++i) {
        const int row = n0 + mt * 16 + l4 * 4 + i;
        const float r0 = accV[0][mt][i], r1 = accV[1][mt][i], r2 = accV[2][mt][i];
        float* xp = x_v + (size_t)row * (NV * 3) + vch * 3;
        xp[0] = r0; xp[1] = r1; xp[2] = r2;
        xv16[(size_t)0 * VPLANE + (size_t)row * NV + vch] = bf16b(r0);
        xv16[(size_t)1 * VPLANE + (size_t)row * NV + vch] = bf16b(r1);
        xv16[(size_t)2 * VPLANE + (size_t)row * NV + vch] = bf16b(r2);
      }
  }
}

// ================= CSR build =================
__global__ void hist_kernel(const int* __restrict__ ei, int* __restrict__ cnt) {
  int e = blockIdx.x * 256 + threadIdx.x;
  if (e < NEDGE) atomicAdd(&cnt[ei[e]], 1);
}

__global__ __launch_bounds__(256) void scan_kernel(
    const int* __restrict__ cnt, int* __restrict__ row_start, int* __restrict__ cursor) {
  __shared__ int part[256];
  const int t = threadIdx.x;
  const int base = t * 63;
  int s = 0;
  for (int i = 0; i < 63; ++i) {
    int idx = base + i;
    if (idx < NNODE) s += cnt[idx];
  }
  part[t] = s;
  __syncthreads();
  if (t == 0) {
    int run = 0;
    for (int i = 0; i < 256; ++i) { int x = part[i]; part[i] = run; run += x; }
  }
  __syncthreads();
  int run = part[t];
  for (int i = 0; i < 63; ++i) {
    int idx = base + i;
    if (idx < NNODE) {
      int c = cnt[idx];   // read before overwrite (cnt aliases cursor)
      row_start[idx] = run;
      cursor[idx] = run;
      run += c;
    }
  }
  if (t == 255) row_start[NNODE] = run;
}

__global__ void scatter_kernel(const int* __restrict__ ei,
                               const float* __restrict__ edge_rshs,
                               int* __restrict__ cursor, int* __restrict__ perm,
                               float4* __restrict__ meta) {
  int e = blockIdx.x * 256 + threadIdx.x;
  if (e < NEDGE) {
    int p = atomicAdd(&cursor[ei[e]], 1);
    perm[e] = p;
    float4 m;
    m.x = __int_as_float(ei[NEDGE + e]);
    m.y = edge_rshs[e * 4 + 1];
    m.z = edge_rshs[e * 4 + 2];
    m.w = edge_rshs[e * 4 + 3];
    meta[p] = m;
  }
}

// ================= edge MLP via MFMA -> bf16 messages at CSR slots ============
// (R14 structure: union SMU, b1/b2 in LDS, unrolled phase 3, bias-init accs)
__global__ __launch_bounds__(256) void edge_mlp_mfma(
    const float* __restrict__ edge_attr, const float* __restrict__ edge_rshs,
    const int* __restrict__ edge_index, const int* __restrict__ perm,
    const unsigned short* __restrict__ W1P, const float* __restrict__ b1,
    const unsigned short* __restrict__ W2P, const float* __restrict__ b2,
    const unsigned short* __restrict__ x_s16, const unsigned short* __restrict__ xv16,
    unsigned short* __restrict__ msg) {
  union SMU {
    struct { unsigned short ea[32 * 48]; unsigned short Hs[32 * 136]; } p1;
    unsigned short msgb[32 * 392];
  };
  __shared__ __align__(16) SMU sm;
  __shared__ __align__(16) unsigned short sj[32][136];
  __shared__ __align__(16) unsigned short vd[32][72];
  __shared__ unsigned short b2s[384];
  __shared__ unsigned short b1s[128];
  __shared__ int src_sh[32];
  __shared__ int slot_sh[32];
  __shared__ float rsh_sh[32][4];
  const int t = threadIdx.x;
  const int lane = t & 63;
  const int w = t >> 6;
  const int l15 = lane & 15;
  const int l4 = lane >> 4;
  const int eblk = blockIdx.x * EPB;

  // ---- phase 0: metadata + bias staging + vectorized ea staging
  if (t < 32 * 4) rsh_sh[t >> 2][t & 3] = edge_rshs[(size_t)eblk * 4 + t];
  if (t < 32) {
    src_sh[t] = edge_index[NEDGE + eblk + t];
    slot_sh[t] = perm[eblk + t];
  }
  for (int i = t; i < 384; i += 256) b2s[i] = bf16b(b2[i]);
  if (t < 128) b1s[t] = bf16b(b1[t]);
  if (t < 128) {
    const int e = t >> 2, q = t & 3;
    const float4 v = *(const float4*)&edge_attr[(size_t)(eblk + e) * NBASIS + q * 4];
    u16x4 tmp;
    tmp[0] = bf16b(v.x); tmp[1] = bf16b(v.y); tmp[2] = bf16b(v.z); tmp[3] = bf16b(v.w);
    *(u16x4*)&sm.p1.ea[e * 48 + q * 4] = tmp;
  } else {
    const int idx = t - 128;           // 128 chunks × 8 shorts of K-pad
    const int e = idx >> 2, q = idx & 3;
    *(u16x8*)&sm.p1.ea[e * 48 + 16 + q * 8] = (u16x8){0, 0, 0, 0, 0, 0, 0, 0};
  }
  __syncthreads();

  // ---- phase 1: GEMM1 (H = silu(ea@W1+b1)) + sj/vd staging from bf16 sources
  {
    const int mt = w & 1, ch = w >> 1;
    const bf16x8 afrag = *(const bf16x8*)&sm.p1.ea[(mt * 16 + l15) * 48 + l4 * 8];
    #pragma unroll
    for (int nt = 0; nt < 4; ++nt) {
      const int ntg = ch * 4 + nt;
      const bf16x8 bfrag = *(const bf16x8*)&W1P[((size_t)ntg * 64 + lane) * 8];
      const int col = ntg * 16 + l15;
      const float bias = bf2f(b1s[col]);
      f32x4 d = {bias, bias, bias, bias};   // bias folded into acc init
      d = __builtin_amdgcn_mfma_f32_16x16x32_bf16(afrag, bfrag, d, 0, 0, 0);
      #pragma unroll
      for (int i = 0; i < 4; ++i) {
        const int e = mt * 16 + l4 * 4 + i;
        sm.p1.Hs[e * 136 + col] = bf16b(silu_f(d[i]));
      }
    }
  }
  // sj: straight u16x8 copy from x_s16 (no conversions)
  #pragma unroll
  for (int p = 0; p < 2; ++p) {
    const int idx = p * 256 + t;
    const int e = idx >> 4, c8 = idx & 15;
    *(u16x8*)&sj[e][c8 * 8] =
        *(const u16x8*)&x_s16[(size_t)src_sh[e] * NS + c8 * 8];
  }
  // vd[e][u] = <v_j[u], r1> * inv_sqrt3 from bf16 planes
  #pragma unroll
  for (int p = 0; p < 8; ++p) {
    const int idx = p * 256 + t;
    const int e = idx >> 6, u = idx & 63;
    const size_t base = (size_t)src_sh[e] * NV + u;
    const float v0 = bf2f(xv16[base]);
    const float v1 = bf2f(xv16[VPLANE + base]);
    const float v2 = bf2f(xv16[2 * VPLANE + base]);
    const float dotv = fmaf(v0, rsh_sh[e][1], fmaf(v1, rsh_sh[e][2], v2 * rsh_sh[e][3]));
    vd[e][u] = bf16b(dotv * 0.5773502691896258f);
  }
  __syncthreads();

  // ---- phase 2: preload A-frags from Hs (then Hs is dead)
  bf16x8 afr[2][4];
  #pragma unroll
  for (int mt = 0; mt < 2; ++mt)
    #pragma unroll
    for (int k = 0; k < 4; ++k)
      afr[mt][k] = *(const bf16x8*)&sm.p1.Hs[(mt * 16 + l15) * 136 + k * 32 + l4 * 8];

  float r0a[2][4];
  #pragma unroll
  for (int mt = 0; mt < 2; ++mt)
    #pragma unroll
    for (int i = 0; i < 4; ++i) r0a[mt][i] = rsh_sh[mt * 16 + l4 * 4 + i][0];
  __syncthreads();   // everyone done reading Hs; msgb region now writable

  // ---- phase 3: GEMM2 + in-LDS epilogue, unrolled; bias folded into acc init
  #pragma unroll
  for (int nn = 0; nn < 6; ++nn) {
    const int nt = w * 6 + nn;
    bf16x8 bfr[4];
    #pragma unroll
    for (int k = 0; k < 4; ++k)
      bfr[k] = *(const bf16x8*)&W2P[(((size_t)nt * 4 + k) * 64 + lane) * 8];
    const int col = nt * 16 + l15;
    const float bias = bf2f(b2s[col]);
    f32x4 acc0 = {bias, bias, bias, bias}, acc1 = {bias, bias, bias, bias};
    #pragma unroll
    for (int k = 0; k < 4; ++k) {
      acc0 = __builtin_amdgcn_mfma_f32_16x16x32_bf16(afr[0][k], bfr[k], acc0, 0, 0, 0);
      acc1 = __builtin_amdgcn_mfma_f32_16x16x32_bf16(afr[1][k], bfr[k], acc1, 0, 0, 0);
    }
    if (col < NS) {
      #pragma unroll
      for (int mt = 0; mt < 2; ++mt)
        #pragma unroll
        for (int i = 0; i < 4; ++i) {
          const int e = mt * 16 + l4 * 4 + i;
          const float wv = mt ? acc1[i] : acc0[i];
          sm.msgb[e * 392 + col] = bf16b(wv * bf2f(sj[e][col]) * r0a[mt][i]);
        }
    } else if (col < NS + NV) {
      const int u = col - NS;
      #pragma unroll
      for (int mt = 0; mt < 2; ++mt)
        #pragma unroll
        for (int i = 0; i < 4; ++i) {
          const int e = mt * 16 + l4 * 4 + i;
          const float wv = mt ? acc1[i] : acc0[i];
          sm.msgb[e * 392 + col] = bf16b(wv * bf2f(vd[e][u]));
        }
    } else if (col < 2 * NS + NV) {
      const int sjc = col - (NS + NV);
      #pragma unroll
      for (int mt = 0; mt < 2; ++mt)
        #pragma unroll
        for (int i = 0; i < 4; ++i) {
          const int e = mt * 16 + l4 * 4 + i;
          const float wv = mt ? acc1[i] : acc0[i];
          sm.msgb[e * 392 + col] = bf16b(wv * bf2f(sj[e][sjc]));
        }
    } else {
      #pragma unroll
      for (int mt = 0; mt < 2; ++mt)
        #pragma unroll
        for (int i = 0; i < 4; ++i) {
          const int e = mt * 16 + l4 * 4 + i;
          const float wv = mt ? acc1[i] : acc0[i];
          sm.msgb[e * 392 + col] = bf16b(wv * r0a[mt][i]);
        }
    }
  }
  __syncthreads();

  // ---- phase 4: coalesced write-out, 768 B per edge row at its CSR slot
  #pragma unroll
  for (int p = 0; p < 6; ++p) {
    const int idx = p * 256 + t;
    const int e = idx / 48, c = idx - e * 48;
    const u16x8 vv = *(const u16x8*)&sm.msgb[e * 392 + c * 8];
    *(u16x8*)&msg[(size_t)slot_sh[e] * 384 + c * 8] = vv;
  }
}

// ===== node_gather: 4 role-waves, batch-8 unrolled loads ======================
__global__ __launch_bounds__(256) void node_gather(
    const unsigned short* __restrict__ msg, const int* __restrict__ row_start,
    const float4* __restrict__ meta, const unsigned short* __restrict__ xv16,
    unsigned short* __restrict__ gs16, unsigned short* __restrict__ gv16) {
  const int n = blockIdx.x;
  const int t = threadIdx.x;
  const int role = t >> 6, ln = t & 63;
  const int beg = row_start[n], end = row_start[n + 1];

  float a0 = 0.f, a1 = 0.f, a2 = 0.f;

  if (role == 0) {
    const unsigned short* mp = msg + (size_t)beg * 384;
    int i = beg;
    for (; i + 8 <= end; i += 8, mp += 3072) {
      unsigned int pr[8]; unsigned short v2[8];
      #pragma unroll
      for (int u = 0; u < 8; ++u) {
        pr[u] = *(const unsigned int*)(mp + u * 384 + 2 * ln);
        v2[u] = mp[u * 384 + 128 + ln];
      }
      #pragma unroll
      for (int u = 0; u < 8; ++u) {
        a0 += __uint_as_float(pr[u] << 16);
        a1 += __uint_as_float(pr[u] & 0xffff0000u);
        a2 += bf2f(v2[u]);
      }
    }
    for (; i < end; ++i, mp += 384) {
      const unsigned int p = *(const unsigned int*)(mp + 2 * ln);
      a0 += __uint_as_float(p << 16);
      a1 += __uint_as_float(p & 0xffff0000u);
      a2 += bf2f(mp[128 + ln]);
    }
    gs16[(size_t)n * 192 + 2 * ln]     = bf16b(silu_f(a0));
    gs16[(size_t)n * 192 + 2 * ln + 1] = bf16b(silu_f(a1));
    gs16[(size_t)n * 192 + 128 + ln]   = bf16b(silu_f(a2));
  } else {
    if (role < 3) {
      const unsigned short* mp = msg + (size_t)beg * 384 + 192 + (role - 1) * 64 + ln;
      int i = beg;
      for (; i + 8 <= end; i += 8, mp += 3072) {
        float4 mt[8]; unsigned short v[8];
        #pragma unroll
        for (int u = 0; u < 8; ++u) { mt[u] = meta[i + u]; v[u] = mp[u * 384]; }
        #pragma unroll
        for (int u = 0; u < 8; ++u) {
          const float m = bf2f(v[u]);
          a0 = fmaf(m, mt[u].y, a0);
          a1 = fmaf(m, mt[u].z, a1);
          a2 = fmaf(m, mt[u].w, a2);
        }
      }
      for (; i < end; ++i, mp += 384) {
        const float4 mt = meta[i];
        const float m = bf2f(mp[0]);
        a0 = fmaf(m, mt.y, a0); a1 = fmaf(m, mt.z, a1); a2 = fmaf(m, mt.w, a2);
      }
    } else {
      const unsigned short* mp = msg + (size_t)beg * 384 + 320 + ln;
      int i = beg;
      for (; i + 8 <= end; i += 8, mp += 3072) {
        float4 mt[8]; unsigned short v[8];
        #pragma unroll
        for (int u = 0; u < 8; ++u) { mt[u] = meta[i + u]; v[u] = mp[u * 384]; }
        unsigned short x0[8], x1[8], x2[8];
        #pragma unroll
        for (int u = 0; u < 8; ++u) {
          const size_t base = (size_t)__float_as_int(mt[u].x) * NV + ln;
          x0[u] = xv16[base]; x1[u] = xv16[VPLANE + base]; x2[u] = xv16[2 * VPLANE + base];
        }
        #pragma unroll
        for (int u = 0; u < 8; ++u) {
          const float m = bf2f(v[u]);
          a0 = fmaf(m, bf2f(x0[u]), a0);
          a1 = fmaf(m, bf2f(x1[u]), a1);
          a2 = fmaf(m, bf2f(x2[u]), a2);
        }
      }
      for (; i < end; ++i, mp += 384) {
        const float4 mt = meta[i];
        const float m = bf2f(mp[0]);
        const size_t base = (size_t)__float_as_int(mt.x) * NV + ln;
        a0 = fmaf(m, bf2f(xv16[base]), a0);
        a1 = fmaf(m, bf2f(xv16[VPLANE + base]), a1);
        a2 = fmaf(m, bf2f(xv16[2 * VPLANE + base]), a2);
      }
    }
    const float nrm = sqrtf(fmaf(a0, a0, fmaf(a1, a1, a2 * a2)) + 1e-12f);
    const float sg = 1.f / (1.f + __expf(-nrm));
    const int u = (role < 3) ? (role - 1) * 64 + ln : 128 + ln;
    gv16[(size_t)0 * GVPLANE + (size_t)n * 192 + u] = bf16b(a0 * sg);
    gv16[(size_t)1 * GVPLANE + (size_t)n * 192 + u] = bf16b(a1 * sg);
    gv16[(size_t)2 * GVPLANE + (size_t)n * 192 + u] = bf16b(a2 * sg);
  }
}

// ===== node_post_mfma: 32 nodes/block; SC folded into packed weights ==========
__global__ __launch_bounds__(256) void node_post_mfma(
    const unsigned short* __restrict__ gs16, const unsigned short* __restrict__ gv16,
    const unsigned short* __restrict__ WqsP, const unsigned short* __restrict__ WqvP,
    const float* __restrict__ x_s, const float* __restrict__ x_v,
    float* __restrict__ out) {
  __shared__ __align__(16) unsigned short gsA[32 * 200];
  __shared__ __align__(16) unsigned short gvA[3][32 * 200];
  const int n0 = blockIdx.x * 32;
  const int t = threadIdx.x;
  const int lane = t & 63;
  const int w = t >> 6;
  const int l15 = lane & 15;
  const int l4 = lane >> 4;

  {
    const unsigned short* sp = gs16 + (size_t)n0 * 192;
    for (int idx = t; idx < 768; idx += 256) {
      const int row = idx / 24, ch = idx - row * 24;
      *(u16x8*)&gsA[row * 200 + ch * 8] = *(const u16x8*)&sp[row * 192 + ch * 8];
    }
    #pragma unroll
    for (int c = 0; c < 3; ++c) {
      const unsigned short* vp = gv16 + (size_t)c * GVPLANE + (size_t)n0 * 192;
      for (int idx = t; idx < 768; idx += 256) {
        const int row = idx / 24, ch = idx - row * 24;
        *(u16x8*)&gvA[c][row * 200 + ch * 8] = *(const u16x8*)&vp[row * 192 + ch * 8];
      }
    }
  }
  __syncthreads();

  f32x4 accS[2][2];
  f32x4 accV[3][2];
  #pragma unroll
  for (int j = 0; j < 2; ++j)
    #pragma unroll
    for (int mt = 0; mt < 2; ++mt) accS[j][mt] = (f32x4){0.f, 0.f, 0.f, 0.f};
  #pragma unroll
  for (int c = 0; c < 3; ++c)
    #pragma unroll
    for (int mt = 0; mt < 2; ++mt) accV[c][mt] = (f32x4){0.f, 0.f, 0.f, 0.f};

  #pragma unroll
  for (int kc = 0; kc < 6; ++kc) {
    bf16x8 aS[2], aV[3][2];
    #pragma unroll
    for (int mt = 0; mt < 2; ++mt)
      aS[mt] = *(const bf16x8*)&gsA[(mt * 16 + l15) * 200 + kc * 32 + l4 * 8];
    #pragma unroll
    for (int c = 0; c < 3; ++c)
      #pragma unroll
      for (int mt = 0; mt < 2; ++mt)
        aV[c][mt] = *(const bf16x8*)&gvA[c][(mt * 16 + l15) * 200 + kc * 32 + l4 * 8];
    const bf16x8 bS0 = *(const bf16x8*)&WqsP[(((size_t)(w * 2 + 0) * 6 + kc) * 64 + lane) * 8];
    const bf16x8 bS1 = *(const bf16x8*)&WqsP[(((size_t)(w * 2 + 1) * 6 + kc) * 64 + lane) * 8];
    const bf16x8 bV  = *(const bf16x8*)&WqvP[(((size_t)w * 6 + kc) * 64 + lane) * 8];
    #pragma unroll
    for (int mt = 0; mt < 2; ++mt) {
      accS[0][mt] = __builtin_amdgcn_mfma_f32_16x16x32_bf16(aS[mt], bS0, accS[0][mt], 0, 0, 0);
      accS[1][mt] = __builtin_amdgcn_mfma_f32_16x16x32_bf16(aS[mt], bS1, accS[1][mt], 0, 0, 0);
    }
    #pragma unroll
    for (int c = 0; c < 3; ++c)
      #pragma unroll
      for (int mt = 0; mt < 2; ++mt)
        accV[c][mt] = __builtin_amdgcn_mfma_f32_16x16x32_bf16(aV[c][mt], bV, accV[c][mt], 0, 0, 0);
  }

  #pragma unroll
  for (int j = 0; j < 2; ++j) {
    const int col = (w * 2 + j) * 16 + l15;
    #pragma unroll
    for (int mt = 0; mt < 2; ++mt)
      #pragma unroll
      for (int i = 0; i < 4; ++i) {
        const int row = n0 + mt * 16 + l4 * 4 + i;
        out[(size_t)row * 320 + col] =
            x_s[(size_t)row * NS + col] + accS[j][mt][i];
      }
  }
  {
    const int vch = w * 16 + l15;
    #pragma unroll
    for (int mt = 0; mt < 2; ++mt)
      #pragma unroll
      for (int i = 0; i < 4; ++i) {
        const int row = n0 + mt * 16 + l4 * 4 + i;
        const float* xvp = x_v + (size_t)row * (NV * 3) + vch * 3;
        float o0 = xvp[0] + accV[0][mt][i];
        float o1 = xvp[1] + accV[1][mt][i];
        float o2 = xvp[2] + accV[2][mt][i];
        float* op = out + (size_t)row * 320 + NS + vch * 3;
        op[0] = o0; op[1] = o1; op[2] = o2;
      }
  }
}

extern "C" void kernel_launch(void* const* d_in, const int* in_sizes, int n_in,
                              void* d_out, int out_size, void* d_ws, size_t ws_size,
                              hipStream_t stream) {
  const float* node_feat = (const float*)d_in[0];
  const float* edge_attr = (const float*)d_in[1];
  const float* edge_rshs = (const float*)d_in[2];
  const int*   edge_index = (const int*)d_in[3];
  const float* Wps = (const float*)d_in[4];
  const float* bps = (const float*)d_in[5];
  const float* Wpv = (const float*)d_in[6];
  const float* W1  = (const float*)d_in[7];
  const float* b1  = (const float*)d_in[8];
  const float* W2  = (const float*)d_in[9];
  const float* b2  = (const float*)d_in[10];
  const float* Wqs = (const float*)d_in[11];
  const float* Wqv = (const float*)d_in[12];
  float* out = (float*)d_out;

  float* x_s = (float*)d_ws;                                            // 16000*128 f32
  float* x_v = x_s + (size_t)NNODE * NS;                                // 16000*192 f32
  unsigned short* msg = (unsigned short*)(x_v + (size_t)NNODE * NV * 3);// 256000*384 bf16
  unsigned short* W1P = msg + (size_t)NEDGE * 384;                      // 4096
  unsigned short* W2P = W1P + 8 * 64 * 8;                               // 49152
  unsigned short* WqsP = W2P + 24 * 4 * 64 * 8;                         // 24576
  unsigned short* WqvP = WqsP + 8 * 6 * 64 * 8;                         // 12288
  unsigned short* WpsP = WqvP + 4 * 6 * 64 * 8;                         // 16384
  unsigned short* WpvP = WpsP + 8 * 4 * 64 * 8;                         // 4096
  unsigned short* x_s16 = WpvP + 4 * 2 * 64 * 8;                        // 2,048,000
  unsigned short* xv16 = x_s16 + (size_t)NNODE * NS;                    // 3,072,000
  unsigned short* gs16 = xv16 + (size_t)3 * VPLANE;                     // 3,072,000
  unsigned short* gv16 = gs16 + (size_t)NNODE * 192;                    // 9,216,000
  float4* meta = (float4*)(gv16 + (size_t)3 * GVPLANE);                 // NEDGE float4
  int* row_start = (int*)(meta + NEDGE);                                // NNODE+1
  int* cursor = row_start + (NNODE + 1);                                // NNODE
  int* perm = cursor + NNODE;                                           // NEDGE

  pack_weights<<<192, 256, 0, stream>>>(W1, W2, Wqs, Wqv, Wps, Wpv,
      W1P, W2P, WqsP, WqvP, WpsP, WpvP, cursor);
  node_pre_mfma<<<NNODE / 32, 256, 0, stream>>>(node_feat, bps, WpsP, WpvP,
      x_s, x_v, x_s16, xv16);
  hist_kernel<<<(NEDGE + 255) / 256, 256, 0, stream>>>(edge_index, cursor);
  scan_kernel<<<1, 256, 0, stream>>>(cursor, row_start, cursor);
  scatter_kernel<<<(NEDGE + 255) / 256, 256, 0, stream>>>(edge_index, edge_rshs,
      cursor, perm, meta);
  edge_mlp_mfma<<<NEDGE / EPB, 256, 0, stream>>>(edge_attr, edge_rshs, edge_index,
      perm, W1P, b1, W2P, b2, x_s16, xv16, msg);
  node_gather<<<NNODE, 256, 0, stream>>>(msg, row_start, meta, xv16, gs16, gv16);
  node_post_mfma<<<NNODE / 32, 256, 0, stream>>>(gs16, gv16, WqsP, WqvP,
      x_s, x_v, out);
}

// Round 16
// 251.181 us; speedup vs baseline: 1.1532x; 1.0037x over previous
//
#include <hip/hip_runtime.h>
#include <hip/hip_bf16.h>

#define NS 128
#define NV 64
#define TPC 192
#define NBASIS 16
#define HID 128
#define WOUT 384
#define NNODE 16000
#define NEDGE 256000
#define EPB 32
#define GVPLANE 3072000   // 16000*192
#define VPLANE  1024000   // 16000*64

typedef __attribute__((ext_vector_type(8))) short bf16x8;
typedef __attribute__((ext_vector_type(8))) unsigned short u16x8;
typedef __attribute__((ext_vector_type(4))) unsigned short u16x4;
typedef __attribute__((ext_vector_type(4))) float f32x4;

__device__ __forceinline__ float silu_f(float x) { return x / (1.0f + __expf(-x)); }
__device__ __forceinline__ unsigned short bf16b(float x) {
  __hip_bfloat16 h = __float2bfloat16(x);
  return *reinterpret_cast<unsigned short*>(&h);
}
__device__ __forceinline__ float bf2f(unsigned short u) {
  return __uint_as_float(((unsigned)u) << 16);
}

// ---- pack W1/W2/Wqs/Wqv/Wps/Wpv into MFMA B-fragment order (bf16, scales folded)
__global__ __launch_bounds__(256) void pack_weights(
    const float* __restrict__ W1, const float* __restrict__ W2,
    const float* __restrict__ Wqs, const float* __restrict__ Wqv,
    const float* __restrict__ Wps, const float* __restrict__ Wpv,
    unsigned short* __restrict__ W1P, unsigned short* __restrict__ W2P,
    unsigned short* __restrict__ WqsP, unsigned short* __restrict__ WqvP,
    unsigned short* __restrict__ WpsP, unsigned short* __restrict__ WpvP,
    int* __restrict__ cursor) {
  const int id = blockIdx.x * 256 + threadIdx.x;
  const int j = id & 7, lane = (id >> 3) & 63;
  const int kj = (lane >> 4) * 8 + j;       // k-offset within 32-chunk
  const int nc = lane & 15;                 // col within 16-tile
  const float SC = 0.07216878364870323f;
  if (id < NNODE) cursor[id] = 0;           // replaces hipMemsetAsync
  if (id < 24 * 4 * 64 * 8) {               // W2P[nt24][kc4][lane][8]
    const int kc = (id >> 9) & 3, nt = id >> 11;
    W2P[id] = bf16b(W2[(kc * 32 + kj) * WOUT + nt * 16 + nc]);
  }
  if (id < 8 * 64 * 8) {                    // W1P[nt8][lane][8] (K=16 padded to 32)
    const int nt = id >> 9;
    W1P[id] = (kj < NBASIS) ? bf16b(W1[kj * HID + nt * 16 + nc]) : (unsigned short)0;
  }
  if (id < 8 * 6 * 64 * 8) {                // WqsP[nt8][kc6][lane][8], SC folded
    const int kc = (id >> 9) % 6, nt = id / (6 * 512);
    WqsP[id] = bf16b(Wqs[(kc * 32 + kj) * NS + nt * 16 + nc] * SC);
  }
  if (id < 4 * 6 * 64 * 8) {                // WqvP[nt4][kc6][lane][8], SC folded
    const int kc = (id >> 9) % 6, nt = id / (6 * 512);
    WqvP[id] = bf16b(Wqv[(kc * 32 + kj) * NV + nt * 16 + nc] * SC);
  }
  if (id < 8 * 4 * 64 * 8) {                // WpsP[nt8][kc4][lane][8], 1/sqrt(128) folded
    const int kc = (id >> 9) & 3, nt = id >> 11;
    WpsP[id] = bf16b(Wps[(kc * 32 + kj) * NS + nt * 16 + nc] * 0.08838834764831845f);
  }
  if (id < 4 * 2 * 64 * 8) {                // WpvP[nt4][kc2][lane][8], 1/8 folded
    const int kc = (id >> 9) & 1, nt = id >> 10;
    WpvP[id] = bf16b(Wpv[(kc * 32 + kj) * NV + nt * 16 + nc] * 0.125f);
  }
}

// ====== node_pre_mfma: 32 nodes/block; x_s/x_v pre-GEMMs via MFMA + edge hist ==
__global__ __launch_bounds__(256) void node_pre_mfma(
    const float* __restrict__ node_feat, const float* __restrict__ bps,
    const unsigned short* __restrict__ WpsP, const unsigned short* __restrict__ WpvP,
    const int* __restrict__ edge_index, int* __restrict__ cnt,
    float* __restrict__ x_s, float* __restrict__ x_v,
    unsigned short* __restrict__ x_s16, unsigned short* __restrict__ xv16) {
  __shared__ __align__(16) unsigned short as_[32 * 136];   // s-part rows, bf16
  __shared__ __align__(16) unsigned short avp[3][32 * 72]; // v planes by c, bf16
  const int n0 = blockIdx.x * 32;
  const int t = threadIdx.x;
  const int lane = t & 63;
  const int w = t >> 6;
  const int l15 = lane & 15;
  const int l4 = lane >> 4;

  // stage s-part (coalesced float4 -> bf16)
  #pragma unroll
  for (int p = 0; p < 4; ++p) {
    const int idx = p * 256 + t;
    const int r = idx >> 5, c4 = idx & 31;
    const float4 v = *(const float4*)&node_feat[(size_t)(n0 + r) * 320 + c4 * 4];
    u16x4 tmp;
    tmp[0] = bf16b(v.x); tmp[1] = bf16b(v.y); tmp[2] = bf16b(v.z); tmp[3] = bf16b(v.w);
    *(u16x4*)&as_[r * 136 + c4 * 4] = tmp;
  }
  // stage v-part into 3 c-planes
  #pragma unroll
  for (int p = 0; p < 8; ++p) {
    const int idx = p * 256 + t;
    const int r = idx >> 6, u = idx & 63;
    const float* vp = &node_feat[(size_t)(n0 + r) * 320 + 128 + u * 3];
    avp[0][r * 72 + u] = bf16b(vp[0]);
    avp[1][r * 72 + u] = bf16b(vp[1]);
    avp[2][r * 72 + u] = bf16b(vp[2]);
  }
  __syncthreads();

  f32x4 accS[2][2];
  #pragma unroll
  for (int jj = 0; jj < 2; ++jj) {
    const float b = bps[(w * 2 + jj) * 16 + l15];
    #pragma unroll
    for (int mt = 0; mt < 2; ++mt) accS[jj][mt] = (f32x4){b, b, b, b};
  }
  f32x4 accV[3][2];
  #pragma unroll
  for (int c = 0; c < 3; ++c)
    #pragma unroll
    for (int mt = 0; mt < 2; ++mt) accV[c][mt] = (f32x4){0.f, 0.f, 0.f, 0.f};

  #pragma unroll
  for (int kc = 0; kc < 4; ++kc) {
    bf16x8 aS[2];
    #pragma unroll
    for (int mt = 0; mt < 2; ++mt)
      aS[mt] = *(const bf16x8*)&as_[(mt * 16 + l15) * 136 + kc * 32 + l4 * 8];
    const bf16x8 bS0 = *(const bf16x8*)&WpsP[(((size_t)(w * 2 + 0) * 4 + kc) * 64 + lane) * 8];
    const bf16x8 bS1 = *(const bf16x8*)&WpsP[(((size_t)(w * 2 + 1) * 4 + kc) * 64 + lane) * 8];
    #pragma unroll
    for (int mt = 0; mt < 2; ++mt) {
      accS[0][mt] = __builtin_amdgcn_mfma_f32_16x16x32_bf16(aS[mt], bS0, accS[0][mt], 0, 0, 0);
      accS[1][mt] = __builtin_amdgcn_mfma_f32_16x16x32_bf16(aS[mt], bS1, accS[1][mt], 0, 0, 0);
    }
  }
  #pragma unroll
  for (int kc = 0; kc < 2; ++kc) {
    const bf16x8 bV = *(const bf16x8*)&WpvP[(((size_t)w * 2 + kc) * 64 + lane) * 8];
    #pragma unroll
    for (int c = 0; c < 3; ++c) {
      bf16x8 aV[2];
      #pragma unroll
      for (int mt = 0; mt < 2; ++mt)
        aV[mt] = *(const bf16x8*)&avp[c][(mt * 16 + l15) * 72 + kc * 32 + l4 * 8];
      #pragma unroll
      for (int mt = 0; mt < 2; ++mt)
        accV[c][mt] = __builtin_amdgcn_mfma_f32_16x16x32_bf16(aV[mt], bV, accV[c][mt], 0, 0, 0);
    }
  }

  #pragma unroll
  for (int jj = 0; jj < 2; ++jj) {
    const int col = (w * 2 + jj) * 16 + l15;
    #pragma unroll
    for (int mt = 0; mt < 2; ++mt)
      #pragma unroll
      for (int i = 0; i < 4; ++i) {
        const int row = n0 + mt * 16 + l4 * 4 + i;
        const float r = accS[jj][mt][i];
        x_s[(size_t)row * NS + col] = r;
        x_s16[(size_t)row * NS + col] = bf16b(r);
      }
  }
  {
    const int vch = w * 16 + l15;
    #pragma unroll
    for (int mt = 0; mt < 2; ++mt)
      #pragma unroll
      for (int i = 0; i < 4; ++i) {
        const int row = n0 + mt * 16 + l4 * 4 + i;
        const float r0 = accV[0][mt][i], r1 = accV[1][mt][i], r2 = accV[2][mt][i];
        float* xp = x_v + (size_t)row * (NV * 3) + vch * 3;
        xp[0] = r0; xp[1] = r1; xp[2] = r2;
        xv16[(size_t)0 * VPLANE + (size_t)row * NV + vch] = bf16b(r0);
        xv16[(size_t)1 * VPLANE + (size_t)row * NV + vch] = bf16b(r1);
        xv16[(size_t)2 * VPLANE + (size_t)row * NV + vch] = bf16b(r2);
      }
  }

  // folded edge histogram (grid-stride; overlaps with other blocks' GEMMs)
  for (int e = blockIdx.x * 256 + t; e < NEDGE; e += gridDim.x * 256)
    atomicAdd(&cnt[edge_index[e]], 1);
}

// ================= CSR scan =================
__global__ __launch_bounds__(256) void scan_kernel(
    const int* __restrict__ cnt, int* __restrict__ row_start, int* __restrict__ cursor) {
  __shared__ int part[256];
  const int t = threadIdx.x;
  const int base = t * 63;
  int s = 0;
  for (int i = 0; i < 63; ++i) {
    int idx = base + i;
    if (idx < NNODE) s += cnt[idx];
  }
  part[t] = s;
  __syncthreads();
  if (t == 0) {
    int run = 0;
    for (int i = 0; i < 256; ++i) { int x = part[i]; part[i] = run; run += x; }
  }
  __syncthreads();
  int run = part[t];
  for (int i = 0; i < 63; ++i) {
    int idx = base + i;
    if (idx < NNODE) {
      int c = cnt[idx];   // read before overwrite (cnt aliases cursor)
      row_start[idx] = run;
      cursor[idx] = run;
      run += c;
    }
  }
  if (t == 255) row_start[NNODE] = run;
}

// ================= edge MLP via MFMA -> bf16 messages at CSR slots ============
// Self-assigns CSR slots (atomicAdd on cursor) and writes meta[slot] — the
// separate scatter_kernel is gone.
__global__ __launch_bounds__(256) void edge_mlp_mfma(
    const float* __restrict__ edge_attr, const float* __restrict__ edge_rshs,
    const int* __restrict__ edge_index, int* __restrict__ cursor,
    float4* __restrict__ meta,
    const unsigned short* __restrict__ W1P, const float* __restrict__ b1,
    const unsigned short* __restrict__ W2P, const float* __restrict__ b2,
    const unsigned short* __restrict__ x_s16, const unsigned short* __restrict__ xv16,
    unsigned short* __restrict__ msg) {
  union SMU {
    struct { unsigned short ea[32 * 48]; unsigned short Hs[32 * 136]; } p1;
    unsigned short msgb[32 * 392];
  };
  __shared__ __align__(16) SMU sm;
  __shared__ __align__(16) unsigned short sj[32][136];
  __shared__ __align__(16) unsigned short vd[32][72];
  __shared__ unsigned short b2s[384];
  __shared__ unsigned short b1s[128];
  __shared__ int src_sh[32];
  __shared__ int slot_sh[32];
  __shared__ float rsh_sh[32][4];
  const int t = threadIdx.x;
  const int lane = t & 63;
  const int w = t >> 6;
  const int l15 = lane & 15;
  const int l4 = lane >> 4;
  const int eblk = blockIdx.x * EPB;

  // ---- phase 0: metadata + slot assignment + bias staging + ea staging
  if (t < 32 * 4) rsh_sh[t >> 2][t & 3] = edge_rshs[(size_t)eblk * 4 + t];
  if (t < 32) {
    const int dst = edge_index[eblk + t];
    slot_sh[t] = atomicAdd(&cursor[dst], 1);
    src_sh[t] = edge_index[NEDGE + eblk + t];
  }
  for (int i = t; i < 384; i += 256) b2s[i] = bf16b(b2[i]);
  if (t < 128) b1s[t] = bf16b(b1[t]);
  if (t < 128) {
    const int e = t >> 2, q = t & 3;
    const float4 v = *(const float4*)&edge_attr[(size_t)(eblk + e) * NBASIS + q * 4];
    u16x4 tmp;
    tmp[0] = bf16b(v.x); tmp[1] = bf16b(v.y); tmp[2] = bf16b(v.z); tmp[3] = bf16b(v.w);
    *(u16x4*)&sm.p1.ea[e * 48 + q * 4] = tmp;
  } else {
    const int idx = t - 128;           // 128 chunks × 8 shorts of K-pad
    const int e = idx >> 2, q = idx & 3;
    *(u16x8*)&sm.p1.ea[e * 48 + 16 + q * 8] = (u16x8){0, 0, 0, 0, 0, 0, 0, 0};
  }
  __syncthreads();

  // meta[slot] = {src, r1} (replaces scatter_kernel)
  if (t < 32) {
    float4 m;
    m.x = __int_as_float(src_sh[t]);
    m.y = rsh_sh[t][1]; m.z = rsh_sh[t][2]; m.w = rsh_sh[t][3];
    meta[slot_sh[t]] = m;
  }

  // ---- phase 1: GEMM1 (H = silu(ea@W1+b1)) + sj/vd staging from bf16 sources
  {
    const int mt = w & 1, ch = w >> 1;
    const bf16x8 afrag = *(const bf16x8*)&sm.p1.ea[(mt * 16 + l15) * 48 + l4 * 8];
    #pragma unroll
    for (int nt = 0; nt < 4; ++nt) {
      const int ntg = ch * 4 + nt;
      const bf16x8 bfrag = *(const bf16x8*)&W1P[((size_t)ntg * 64 + lane) * 8];
      const int col = ntg * 16 + l15;
      const float bias = bf2f(b1s[col]);
      f32x4 d = {bias, bias, bias, bias};
      d = __builtin_amdgcn_mfma_f32_16x16x32_bf16(afrag, bfrag, d, 0, 0, 0);
      #pragma unroll
      for (int i = 0; i < 4; ++i) {
        const int e = mt * 16 + l4 * 4 + i;
        sm.p1.Hs[e * 136 + col] = bf16b(silu_f(d[i]));
      }
    }
  }
  // sj: straight u16x8 copy from x_s16
  #pragma unroll
  for (int p = 0; p < 2; ++p) {
    const int idx = p * 256 + t;
    const int e = idx >> 4, c8 = idx & 15;
    *(u16x8*)&sj[e][c8 * 8] =
        *(const u16x8*)&x_s16[(size_t)src_sh[e] * NS + c8 * 8];
  }
  // vd[e][u] = <v_j[u], r1> * inv_sqrt3 from bf16 planes
  #pragma unroll
  for (int p = 0; p < 8; ++p) {
    const int idx = p * 256 + t;
    const int e = idx >> 6, u = idx & 63;
    const size_t base = (size_t)src_sh[e] * NV + u;
    const float v0 = bf2f(xv16[base]);
    const float v1 = bf2f(xv16[VPLANE + base]);
    const float v2 = bf2f(xv16[2 * VPLANE + base]);
    const float dotv = fmaf(v0, rsh_sh[e][1], fmaf(v1, rsh_sh[e][2], v2 * rsh_sh[e][3]));
    vd[e][u] = bf16b(dotv * 0.5773502691896258f);
  }
  __syncthreads();

  // ---- phase 2: preload A-frags from Hs (then Hs is dead)
  bf16x8 afr[2][4];
  #pragma unroll
  for (int mt = 0; mt < 2; ++mt)
    #pragma unroll
    for (int k = 0; k < 4; ++k)
      afr[mt][k] = *(const bf16x8*)&sm.p1.Hs[(mt * 16 + l15) * 136 + k * 32 + l4 * 8];

  float r0a[2][4];
  #pragma unroll
  for (int mt = 0; mt < 2; ++mt)
    #pragma unroll
    for (int i = 0; i < 4; ++i) r0a[mt][i] = rsh_sh[mt * 16 + l4 * 4 + i][0];
  __syncthreads();   // everyone done reading Hs; msgb region now writable

  // ---- phase 3: GEMM2 + in-LDS epilogue
  #pragma unroll
  for (int nn = 0; nn < 6; ++nn) {
    const int nt = w * 6 + nn;
    bf16x8 bfr[4];
    #pragma unroll
    for (int k = 0; k < 4; ++k)
      bfr[k] = *(const bf16x8*)&W2P[(((size_t)nt * 4 + k) * 64 + lane) * 8];
    const int col = nt * 16 + l15;
    const float bias = bf2f(b2s[col]);
    f32x4 acc0 = {bias, bias, bias, bias}, acc1 = {bias, bias, bias, bias};
    #pragma unroll
    for (int k = 0; k < 4; ++k) {
      acc0 = __builtin_amdgcn_mfma_f32_16x16x32_bf16(afr[0][k], bfr[k], acc0, 0, 0, 0);
      acc1 = __builtin_amdgcn_mfma_f32_16x16x32_bf16(afr[1][k], bfr[k], acc1, 0, 0, 0);
    }
    if (col < NS) {
      #pragma unroll
      for (int mt = 0; mt < 2; ++mt)
        #pragma unroll
        for (int i = 0; i < 4; ++i) {
          const int e = mt * 16 + l4 * 4 + i;
          const float wv = mt ? acc1[i] : acc0[i];
          sm.msgb[e * 392 + col] = bf16b(wv * bf2f(sj[e][col]) * r0a[mt][i]);
        }
    } else if (col < NS + NV) {
      const int u = col - NS;
      #pragma unroll
      for (int mt = 0; mt < 2; ++mt)
        #pragma unroll
        for (int i = 0; i < 4; ++i) {
          const int e = mt * 16 + l4 * 4 + i;
          const float wv = mt ? acc1[i] : acc0[i];
          sm.msgb[e * 392 + col] = bf16b(wv * bf2f(vd[e][u]));
        }
    } else if (col < 2 * NS + NV) {
      const int sjc = col - (NS + NV);
      #pragma unroll
      for (int mt = 0; mt < 2; ++mt)
        #pragma unroll
        for (int i = 0; i < 4; ++i) {
          const int e = mt * 16 + l4 * 4 + i;
          const float wv = mt ? acc1[i] : acc0[i];
          sm.msgb[e * 392 + col] = bf16b(wv * bf2f(sj[e][sjc]));
        }
    } else {
      #pragma unroll
      for (int mt = 0; mt < 2; ++mt)
        #pragma unroll
        for (int i = 0; i < 4; ++i) {
          const int e = mt * 16 + l4 * 4 + i;
          const float wv = mt ? acc1[i] : acc0[i];
          sm.msgb[e * 392 + col] = bf16b(wv * r0a[mt][i]);
        }
    }
  }
  __syncthreads();

  // ---- phase 4: coalesced write-out, 768 B per edge row at its CSR slot
  #pragma unroll
  for (int p = 0; p < 6; ++p) {
    const int idx = p * 256 + t;
    const int e = idx / 48, c = idx - e * 48;
    const u16x8 vv = *(const u16x8*)&sm.msgb[e * 392 + c * 8];
    *(u16x8*)&msg[(size_t)slot_sh[e] * 384 + c * 8] = vv;
  }
}

// ===== node_gather: 4 role-waves, batch-16/8 unrolled loads ===================
__global__ __launch_bounds__(256) void node_gather(
    const unsigned short* __restrict__ msg, const int* __restrict__ row_start,
    const float4* __restrict__ meta, const unsigned short* __restrict__ xv16,
    unsigned short* __restrict__ gs16, unsigned short* __restrict__ gv16) {
  const int n = blockIdx.x;
  const int t = threadIdx.x;
  const int role = t >> 6, ln = t & 63;
  const int beg = row_start[n], end = row_start[n + 1];

  float a0 = 0.f, a1 = 0.f, a2 = 0.f;

  if (role == 0) {
    const unsigned short* mp = msg + (size_t)beg * 384;
    int i = beg;
    for (; i + 16 <= end; i += 16, mp += 6144) {
      unsigned int pr[16]; unsigned short v2[16];
      #pragma unroll
      for (int u = 0; u < 16; ++u) {
        pr[u] = *(const unsigned int*)(mp + u * 384 + 2 * ln);
        v2[u] = mp[u * 384 + 128 + ln];
      }
      #pragma unroll
      for (int u = 0; u < 16; ++u) {
        a0 += __uint_as_float(pr[u] << 16);
        a1 += __uint_as_float(pr[u] & 0xffff0000u);
        a2 += bf2f(v2[u]);
      }
    }
    for (; i + 8 <= end; i += 8, mp += 3072) {
      unsigned int pr[8]; unsigned short v2[8];
      #pragma unroll
      for (int u = 0; u < 8; ++u) {
        pr[u] = *(const unsigned int*)(mp + u * 384 + 2 * ln);
        v2[u] = mp[u * 384 + 128 + ln];
      }
      #pragma unroll
      for (int u = 0; u < 8; ++u) {
        a0 += __uint_as_float(pr[u] << 16);
        a1 += __uint_as_float(pr[u] & 0xffff0000u);
        a2 += bf2f(v2[u]);
      }
    }
    for (; i < end; ++i, mp += 384) {
      const unsigned int p = *(const unsigned int*)(mp + 2 * ln);
      a0 += __uint_as_float(p << 16);
      a1 += __uint_as_float(p & 0xffff0000u);
      a2 += bf2f(mp[128 + ln]);
    }
    gs16[(size_t)n * 192 + 2 * ln]     = bf16b(silu_f(a0));
    gs16[(size_t)n * 192 + 2 * ln + 1] = bf16b(silu_f(a1));
    gs16[(size_t)n * 192 + 128 + ln]   = bf16b(silu_f(a2));
  } else {
    if (role < 3) {
      const unsigned short* mp = msg + (size_t)beg * 384 + 192 + (role - 1) * 64 + ln;
      int i = beg;
      for (; i + 16 <= end; i += 16, mp += 6144) {
        float4 mt[16]; unsigned short v[16];
        #pragma unroll
        for (int u = 0; u < 16; ++u) { mt[u] = meta[i + u]; v[u] = mp[u * 384]; }
        #pragma unroll
        for (int u = 0; u < 16; ++u) {
          const float m = bf2f(v[u]);
          a0 = fmaf(m, mt[u].y, a0);
          a1 = fmaf(m, mt[u].z, a1);
          a2 = fmaf(m, mt[u].w, a2);
        }
      }
      for (; i + 8 <= end; i += 8, mp += 3072) {
        float4 mt[8]; unsigned short v[8];
        #pragma unroll
        for (int u = 0; u < 8; ++u) { mt[u] = meta[i + u]; v[u] = mp[u * 384]; }
        #pragma unroll
        for (int u = 0; u < 8; ++u) {
          const float m = bf2f(v[u]);
          a0 = fmaf(m, mt[u].y, a0);
          a1 = fmaf(m, mt[u].z, a1);
          a2 = fmaf(m, mt[u].w, a2);
        }
      }
      for (; i < end; ++i, mp += 384) {
        const float4 mt = meta[i];
        const float m = bf2f(mp[0]);
        a0 = fmaf(m, mt.y, a0); a1 = fmaf(m, mt.z, a1); a2 = fmaf(m, mt.w, a2);
      }
    } else {
      const unsigned short* mp = msg + (size_t)beg * 384 + 320 + ln;
      int i = beg;
      for (; i + 8 <= end; i += 8, mp += 3072) {
        float4 mt[8]; unsigned short v[8];
        #pragma unroll
        for (int u = 0; u < 8; ++u) { mt[u] = meta[i + u]; v[u] = mp[u * 384]; }
        unsigned short x0[8], x1[8], x2[8];
        #pragma unroll
        for (int u = 0; u < 8; ++u) {
          const size_t base = (size_t)__float_as_int(mt[u].x) * NV + ln;
          x0[u] = xv16[base]; x1[u] = xv16[VPLANE + base]; x2[u] = xv16[2 * VPLANE + base];
        }
        #pragma unroll
        for (int u = 0; u < 8; ++u) {
          const float m = bf2f(v[u]);
          a0 = fmaf(m, bf2f(x0[u]), a0);
          a1 = fmaf(m, bf2f(x1[u]), a1);
          a2 = fmaf(m, bf2f(x2[u]), a2);
        }
      }
      for (; i < end; ++i, mp += 384) {
        const float4 mt = meta[i];
        const float m = bf2f(mp[0]);
        const size_t base = (size_t)__float_as_int(mt.x) * NV + ln;
        a0 = fmaf(m, bf2f(xv16[base]), a0);
        a1 = fmaf(m, bf2f(xv16[VPLANE + base]), a1);
        a2 = fmaf(m, bf2f(xv16[2 * VPLANE + base]), a2);
      }
    }
    const float nrm = sqrtf(fmaf(a0, a0, fmaf(a1, a1, a2 * a2)) + 1e-12f);
    const float sg = 1.f / (1.f + __expf(-nrm));
    const int u = (role < 3) ? (role - 1) * 64 + ln : 128 + ln;
    gv16[(size_t)0 * GVPLANE + (size_t)n * 192 + u] = bf16b(a0 * sg);
    gv16[(size_t)1 * GVPLANE + (size_t)n * 192 + u] = bf16b(a1 * sg);
    gv16[(size_t)2 * GVPLANE + (size_t)n * 192 + u] = bf16b(a2 * sg);
  }
}

// ===== node_post_mfma: 32 nodes/block; SC folded into packed weights ==========
__global__ __launch_bounds__(256) void node_post_mfma(
    const unsigned short* __restrict__ gs16, const unsigned short* __restrict__ gv16,
    const unsigned short* __restrict__ WqsP, const unsigned short* __restrict__ WqvP,
    const float* __restrict__ x_s, const float* __restrict__ x_v,
    float* __restrict__ out) {
  __shared__ __align__(16) unsigned short gsA[32 * 200];
  __shared__ __align__(16) unsigned short gvA[3][32 * 200];
  const int n0 = blockIdx.x * 32;
  const int t = threadIdx.x;
  const int lane = t & 63;
  const int w = t >> 6;
  const int l15 = lane & 15;
  const int l4 = lane >> 4;

  {
    const unsigned short* sp = gs16 + (size_t)n0 * 192;
    for (int idx = t; idx < 768; idx += 256) {
      const int row = idx / 24, ch = idx - row * 24;
      *(u16x8*)&gsA[row * 200 + ch * 8] = *(const u16x8*)&sp[row * 192 + ch * 8];
    }
    #pragma unroll
    for (int c = 0; c < 3; ++c) {
      const unsigned short* vp = gv16 + (size_t)c * GVPLANE + (size_t)n0 * 192;
      for (int idx = t; idx < 768; idx += 256) {
        const int row = idx / 24, ch = idx - row * 24;
        *(u16x8*)&gvA[c][row * 200 + ch * 8] = *(const u16x8*)&vp[row * 192 + ch * 8];
      }
    }
  }
  __syncthreads();

  f32x4 accS[2][2];
  f32x4 accV[3][2];
  #pragma unroll
  for (int j = 0; j < 2; ++j)
    #pragma unroll
    for (int mt = 0; mt < 2; ++mt) accS[j][mt] = (f32x4){0.f, 0.f, 0.f, 0.f};
  #pragma unroll
  for (int c = 0; c < 3; ++c)
    #pragma unroll
    for (int mt = 0; mt < 2; ++mt) accV[c][mt] = (f32x4){0.f, 0.f, 0.f, 0.f};

  #pragma unroll
  for (int kc = 0; kc < 6; ++kc) {
    bf16x8 aS[2], aV[3][2];
    #pragma unroll
    for (int mt = 0; mt < 2; ++mt)
      aS[mt] = *(const bf16x8*)&gsA[(mt * 16 + l15) * 200 + kc * 32 + l4 * 8];
    #pragma unroll
    for (int c = 0; c < 3; ++c)
      #pragma unroll
      for (int mt = 0; mt < 2; ++mt)
        aV[c][mt] = *(const bf16x8*)&gvA[c][(mt * 16 + l15) * 200 + kc * 32 + l4 * 8];
    const bf16x8 bS0 = *(const bf16x8*)&WqsP[(((size_t)(w * 2 + 0) * 6 + kc) * 64 + lane) * 8];
    const bf16x8 bS1 = *(const bf16x8*)&WqsP[(((size_t)(w * 2 + 1) * 6 + kc) * 64 + lane) * 8];
    const bf16x8 bV  = *(const bf16x8*)&WqvP[(((size_t)w * 6 + kc) * 64 + lane) * 8];
    #pragma unroll
    for (int mt = 0; mt < 2; ++mt) {
      accS[0][mt] = __builtin_amdgcn_mfma_f32_16x16x32_bf16(aS[mt], bS0, accS[0][mt], 0, 0, 0);
      accS[1][mt] = __builtin_amdgcn_mfma_f32_16x16x32_bf16(aS[mt], bS1, accS[1][mt], 0, 0, 0);
    }
    #pragma unroll
    for (int c = 0; c < 3; ++c)
      #pragma unroll
      for (int mt = 0; mt < 2; ++mt)
        accV[c][mt] = __builtin_amdgcn_mfma_f32_16x16x32_bf16(aV[c][mt], bV, accV[c][mt], 0, 0, 0);
  }

  #pragma unroll
  for (int j = 0; j < 2; ++j) {
    const int col = (w * 2 + j) * 16 + l15;
    #pragma unroll
    for (int mt = 0; mt < 2; ++mt)
      #pragma unroll
      for (int i = 0; i < 4; ++i) {
        const int row = n0 + mt * 16 + l4 * 4 + i;
        out[(size_t)row * 320 + col] =
            x_s[(size_t)row * NS + col] + accS[j][mt][i];
      }
  }
  {
    const int vch = w * 16 + l15;
    #pragma unroll
    for (int mt = 0; mt < 2; ++mt)
      #pragma unroll
      for (int i = 0; i < 4; ++i) {
        const int row = n0 + mt * 16 + l4 * 4 + i;
        const float* xvp = x_v + (size_t)row * (NV * 3) + vch * 3;
        float o0 = xvp[0] + accV[0][mt][i];
        float o1 = xvp[1] + accV[1][mt][i];
        float o2 = xvp[2] + accV[2][mt][i];
        float* op = out + (size_t)row * 320 + NS + vch * 3;
        op[0] = o0; op[1] = o1; op[2] = o2;
      }
  }
}

extern "C" void kernel_launch(void* const* d_in, const int* in_sizes, int n_in,
                              void* d_out, int out_size, void* d_ws, size_t ws_size,
                              hipStream_t stream) {
  const float* node_feat = (const float*)d_in[0];
  const float* edge_attr = (const float*)d_in[1];
  const float* edge_rshs = (const float*)d_in[2];
  const int*   edge_index = (const int*)d_in[3];
  const float* Wps = (const float*)d_in[4];
  const float* bps = (const float*)d_in[5];
  const float* Wpv = (const float*)d_in[6];
  const float* W1  = (const float*)d_in[7];
  const float* b1  = (const float*)d_in[8];
  const float* W2  = (const float*)d_in[9];
  const float* b2  = (const float*)d_in[10];
  const float* Wqs = (const float*)d_in[11];
  const float* Wqv = (const float*)d_in[12];
  float* out = (float*)d_out;

  float* x_s = (float*)d_ws;                                            // 16000*128 f32
  float* x_v = x_s + (size_t)NNODE * NS;                                // 16000*192 f32
  unsigned short* msg = (unsigned short*)(x_v + (size_t)NNODE * NV * 3);// 256000*384 bf16
  unsigned short* W1P = msg + (size_t)NEDGE * 384;                      // 4096
  unsigned short* W2P = W1P + 8 * 64 * 8;                               // 49152
  unsigned short* WqsP = W2P + 24 * 4 * 64 * 8;                         // 24576
  unsigned short* WqvP = WqsP + 8 * 6 * 64 * 8;                         // 12288
  unsigned short* WpsP = WqvP + 4 * 6 * 64 * 8;                         // 16384
  unsigned short* WpvP = WpsP + 8 * 4 * 64 * 8;                         // 4096
  unsigned short* x_s16 = WpvP + 4 * 2 * 64 * 8;                        // 2,048,000
  unsigned short* xv16 = x_s16 + (size_t)NNODE * NS;                    // 3,072,000
  unsigned short* gs16 = xv16 + (size_t)3 * VPLANE;                     // 3,072,000
  unsigned short* gv16 = gs16 + (size_t)NNODE * 192;                    // 9,216,000
  float4* meta = (float4*)(gv16 + (size_t)3 * GVPLANE);                 // NEDGE float4
  int* row_start = (int*)(meta + NEDGE);                                // NNODE+1
  int* cursor = row_start + (NNODE + 1);                                // NNODE

  pack_weights<<<192, 256, 0, stream>>>(W1, W2, Wqs, Wqv, Wps, Wpv,
      W1P, W2P, WqsP, WqvP, WpsP, WpvP, cursor);
  node_pre_mfma<<<NNODE / 32, 256, 0, stream>>>(node_feat, bps, WpsP, WpvP,
      edge_index, cursor, x_s, x_v, x_s16, xv16);
  scan_kernel<<<1, 256, 0, stream>>>(cursor, row_start, cursor);
  edge_mlp_mfma<<<NEDGE / EPB, 256, 0, stream>>>(edge_attr, edge_rshs, edge_index,
      cursor, meta, W1P, b1, W2P, b2, x_s16, xv16, msg);
  node_gather<<<NNODE, 256, 0, stream>>>(msg, row_start, meta, xv16, gs16, gv16);
  node_post_mfma<<<NNODE / 32, 256, 0, stream>>>(gs16, gv16, WqsP, WqvP,
      x_s, x_v, out);
}

// Round 17
// 249.660 us; speedup vs baseline: 1.1602x; 1.0061x over previous
//
#include <hip/hip_runtime.h>
#include <hip/hip_bf16.h>

#define NS 128
#define NV 64
#define TPC 192
#define NBASIS 16
#define HID 128
#define WOUT 384
#define NNODE 16000
#define NEDGE 256000
#define EPB 32
#define GVPLANE 3072000   // 16000*192
#define VPLANE  1024000   // 16000*64

typedef __attribute__((ext_vector_type(8))) short bf16x8;
typedef __attribute__((ext_vector_type(8))) unsigned short u16x8;
typedef __attribute__((ext_vector_type(4))) unsigned short u16x4;
typedef __attribute__((ext_vector_type(4))) float f32x4;

__device__ __forceinline__ float silu_f(float x) { return x / (1.0f + __expf(-x)); }
__device__ __forceinline__ unsigned short bf16b(float x) {
  __hip_bfloat16 h = __float2bfloat16(x);
  return *reinterpret_cast<unsigned short*>(&h);
}
__device__ __forceinline__ float bf2f(unsigned short u) {
  return __uint_as_float(((unsigned)u) << 16);
}

// ---- pack W1/W2/Wqs/Wqv/Wps/Wpv into MFMA B-fragment order (bf16, scales folded)
__global__ __launch_bounds__(256) void pack_weights(
    const float* __restrict__ W1, const float* __restrict__ W2,
    const float* __restrict__ Wqs, const float* __restrict__ Wqv,
    const float* __restrict__ Wps, const float* __restrict__ Wpv,
    unsigned short* __restrict__ W1P, unsigned short* __restrict__ W2P,
    unsigned short* __restrict__ WqsP, unsigned short* __restrict__ WqvP,
    unsigned short* __restrict__ WpsP, unsigned short* __restrict__ WpvP,
    int* __restrict__ cursor) {
  const int id = blockIdx.x * 256 + threadIdx.x;
  const int j = id & 7, lane = (id >> 3) & 63;
  const int kj = (lane >> 4) * 8 + j;       // k-offset within 32-chunk
  const int nc = lane & 15;                 // col within 16-tile
  const float SC = 0.07216878364870323f;
  if (id < NNODE) cursor[id] = 0;           // replaces hipMemsetAsync
  if (id < 24 * 4 * 64 * 8) {               // W2P[nt24][kc4][lane][8]
    const int kc = (id >> 9) & 3, nt = id >> 11;
    W2P[id] = bf16b(W2[(kc * 32 + kj) * WOUT + nt * 16 + nc]);
  }
  if (id < 8 * 64 * 8) {                    // W1P[nt8][lane][8] (K=16 padded to 32)
    const int nt = id >> 9;
    W1P[id] = (kj < NBASIS) ? bf16b(W1[kj * HID + nt * 16 + nc]) : (unsigned short)0;
  }
  if (id < 8 * 6 * 64 * 8) {                // WqsP[nt8][kc6][lane][8], SC folded
    const int kc = (id >> 9) % 6, nt = id / (6 * 512);
    WqsP[id] = bf16b(Wqs[(kc * 32 + kj) * NS + nt * 16 + nc] * SC);
  }
  if (id < 4 * 6 * 64 * 8) {                // WqvP[nt4][kc6][lane][8], SC folded
    const int kc = (id >> 9) % 6, nt = id / (6 * 512);
    WqvP[id] = bf16b(Wqv[(kc * 32 + kj) * NV + nt * 16 + nc] * SC);
  }
  if (id < 8 * 4 * 64 * 8) {                // WpsP[nt8][kc4][lane][8], 1/sqrt(128) folded
    const int kc = (id >> 9) & 3, nt = id >> 11;
    WpsP[id] = bf16b(Wps[(kc * 32 + kj) * NS + nt * 16 + nc] * 0.08838834764831845f);
  }
  if (id < 4 * 2 * 64 * 8) {                // WpvP[nt4][kc2][lane][8], 1/8 folded
    const int kc = (id >> 9) & 1, nt = id >> 10;
    WpvP[id] = bf16b(Wpv[(kc * 32 + kj) * NV + nt * 16 + nc] * 0.125f);
  }
}

// ====== node_pre_mfma: 32 nodes/block; x_s/x_v pre-GEMMs via MFMA + edge hist ==
__global__ __launch_bounds__(256) void node_pre_mfma(
    const float* __restrict__ node_feat, const float* __restrict__ bps,
    const unsigned short* __restrict__ WpsP, const unsigned short* __restrict__ WpvP,
    const int* __restrict__ edge_index, int* __restrict__ cnt,
    float* __restrict__ x_s, float* __restrict__ x_v,
    unsigned short* __restrict__ x_s16, unsigned short* __restrict__ xv16) {
  __shared__ __align__(16) unsigned short as_[32 * 136];   // s-part rows, bf16
  __shared__ __align__(16) unsigned short avp[3][32 * 72]; // v planes by c, bf16
  const int n0 = blockIdx.x * 32;
  const int t = threadIdx.x;
  const int lane = t & 63;
  const int w = t >> 6;
  const int l15 = lane & 15;
  const int l4 = lane >> 4;

  // stage s-part (coalesced float4 -> bf16)
  #pragma unroll
  for (int p = 0; p < 4; ++p) {
    const int idx = p * 256 + t;
    const int r = idx >> 5, c4 = idx & 31;
    const float4 v = *(const float4*)&node_feat[(size_t)(n0 + r) * 320 + c4 * 4];
    u16x4 tmp;
    tmp[0] = bf16b(v.x); tmp[1] = bf16b(v.y); tmp[2] = bf16b(v.z); tmp[3] = bf16b(v.w);
    *(u16x4*)&as_[r * 136 + c4 * 4] = tmp;
  }
  // stage v-part into 3 c-planes
  #pragma unroll
  for (int p = 0; p < 8; ++p) {
    const int idx = p * 256 + t;
    const int r = idx >> 6, u = idx & 63;
    const float* vp = &node_feat[(size_t)(n0 + r) * 320 + 128 + u * 3];
    avp[0][r * 72 + u] = bf16b(vp[0]);
    avp[1][r * 72 + u] = bf16b(vp[1]);
    avp[2][r * 72 + u] = bf16b(vp[2]);
  }
  __syncthreads();

  f32x4 accS[2][2];
  #pragma unroll
  for (int jj = 0; jj < 2; ++jj) {
    const float b = bps[(w * 2 + jj) * 16 + l15];
    #pragma unroll
    for (int mt = 0; mt < 2; ++mt) accS[jj][mt] = (f32x4){b, b, b, b};
  }
  f32x4 accV[3][2];
  #pragma unroll
  for (int c = 0; c < 3; ++c)
    #pragma unroll
    for (int mt = 0; mt < 2; ++mt) accV[c][mt] = (f32x4){0.f, 0.f, 0.f, 0.f};

  #pragma unroll
  for (int kc = 0; kc < 4; ++kc) {
    bf16x8 aS[2];
    #pragma unroll
    for (int mt = 0; mt < 2; ++mt)
      aS[mt] = *(const bf16x8*)&as_[(mt * 16 + l15) * 136 + kc * 32 + l4 * 8];
    const bf16x8 bS0 = *(const bf16x8*)&WpsP[(((size_t)(w * 2 + 0) * 4 + kc) * 64 + lane) * 8];
    const bf16x8 bS1 = *(const bf16x8*)&WpsP[(((size_t)(w * 2 + 1) * 4 + kc) * 64 + lane) * 8];
    #pragma unroll
    for (int mt = 0; mt < 2; ++mt) {
      accS[0][mt] = __builtin_amdgcn_mfma_f32_16x16x32_bf16(aS[mt], bS0, accS[0][mt], 0, 0, 0);
      accS[1][mt] = __builtin_amdgcn_mfma_f32_16x16x32_bf16(aS[mt], bS1, accS[1][mt], 0, 0, 0);
    }
  }
  #pragma unroll
  for (int kc = 0; kc < 2; ++kc) {
    const bf16x8 bV = *(const bf16x8*)&WpvP[(((size_t)w * 2 + kc) * 64 + lane) * 8];
    #pragma unroll
    for (int c = 0; c < 3; ++c) {
      bf16x8 aV[2];
      #pragma unroll
      for (int mt = 0; mt < 2; ++mt)
        aV[mt] = *(const bf16x8*)&avp[c][(mt * 16 + l15) * 72 + kc * 32 + l4 * 8];
      #pragma unroll
      for (int mt = 0; mt < 2; ++mt)
        accV[c][mt] = __builtin_amdgcn_mfma_f32_16x16x32_bf16(aV[mt], bV, accV[c][mt], 0, 0, 0);
    }
  }

  #pragma unroll
  for (int jj = 0; jj < 2; ++jj) {
    const int col = (w * 2 + jj) * 16 + l15;
    #pragma unroll
    for (int mt = 0; mt < 2; ++mt)
      #pragma unroll
      for (int i = 0; i < 4; ++i) {
        const int row = n0 + mt * 16 + l4 * 4 + i;
        const float r = accS[jj][mt][i];
        x_s[(size_t)row * NS + col] = r;
        x_s16[(size_t)row * NS + col] = bf16b(r);
      }
  }
  {
    const int vch = w * 16 + l15;
    #pragma unroll
    for (int mt = 0; mt < 2; ++mt)
      #pragma unroll
      for (int i = 0; i < 4; ++i) {
        const int row = n0 + mt * 16 + l4 * 4 + i;
        const float r0 = accV[0][mt][i], r1 = accV[1][mt][i], r2 = accV[2][mt][i];
        float* xp = x_v + (size_t)row * (NV * 3) + vch * 3;
        xp[0] = r0; xp[1] = r1; xp[2] = r2;
        xv16[(size_t)0 * VPLANE + (size_t)row * NV + vch] = bf16b(r0);
        xv16[(size_t)1 * VPLANE + (size_t)row * NV + vch] = bf16b(r1);
        xv16[(size_t)2 * VPLANE + (size_t)row * NV + vch] = bf16b(r2);
      }
  }

  // folded edge histogram (grid-stride; overlaps with other blocks' GEMMs)
  for (int e = blockIdx.x * 256 + t; e < NEDGE; e += gridDim.x * 256)
    atomicAdd(&cnt[edge_index[e]], 1);
}

// ================= CSR scan =================
__global__ __launch_bounds__(256) void scan_kernel(
    const int* __restrict__ cnt, int* __restrict__ row_start, int* __restrict__ cursor) {
  __shared__ int part[256];
  const int t = threadIdx.x;
  const int base = t * 63;
  int s = 0;
  for (int i = 0; i < 63; ++i) {
    int idx = base + i;
    if (idx < NNODE) s += cnt[idx];
  }
  part[t] = s;
  __syncthreads();
  if (t == 0) {
    int run = 0;
    for (int i = 0; i < 256; ++i) { int x = part[i]; part[i] = run; run += x; }
  }
  __syncthreads();
  int run = part[t];
  for (int i = 0; i < 63; ++i) {
    int idx = base + i;
    if (idx < NNODE) {
      int c = cnt[idx];   // read before overwrite (cnt aliases cursor)
      row_start[idx] = run;
      cursor[idx] = run;
      run += c;
    }
  }
  if (t == 255) row_start[NNODE] = run;
}

// scatter: assign CSR slot, record perm (edge->slot) and per-slot meta {src, r1}
__global__ void scatter_kernel(const int* __restrict__ ei,
                               const float* __restrict__ edge_rshs,
                               int* __restrict__ cursor, int* __restrict__ perm,
                               float4* __restrict__ meta) {
  int e = blockIdx.x * 256 + threadIdx.x;
  if (e < NEDGE) {
    int p = atomicAdd(&cursor[ei[e]], 1);
    perm[e] = p;
    float4 m;
    m.x = __int_as_float(ei[NEDGE + e]);
    m.y = edge_rshs[e * 4 + 1];
    m.z = edge_rshs[e * 4 + 2];
    m.w = edge_rshs[e * 4 + 3];
    meta[p] = m;
  }
}

// ================= edge MLP via MFMA -> bf16 messages at CSR slots ============
// (R15 structure: perm precomputed by scatter_kernel; pure compute here)
__global__ __launch_bounds__(256) void edge_mlp_mfma(
    const float* __restrict__ edge_attr, const float* __restrict__ edge_rshs,
    const int* __restrict__ edge_index, const int* __restrict__ perm,
    const unsigned short* __restrict__ W1P, const float* __restrict__ b1,
    const unsigned short* __restrict__ W2P, const float* __restrict__ b2,
    const unsigned short* __restrict__ x_s16, const unsigned short* __restrict__ xv16,
    unsigned short* __restrict__ msg) {
  union SMU {
    struct { unsigned short ea[32 * 48]; unsigned short Hs[32 * 136]; } p1;
    unsigned short msgb[32 * 392];
  };
  __shared__ __align__(16) SMU sm;
  __shared__ __align__(16) unsigned short sj[32][136];
  __shared__ __align__(16) unsigned short vd[32][72];
  __shared__ unsigned short b2s[384];
  __shared__ unsigned short b1s[128];
  __shared__ int src_sh[32];
  __shared__ int slot_sh[32];
  __shared__ float rsh_sh[32][4];
  const int t = threadIdx.x;
  const int lane = t & 63;
  const int w = t >> 6;
  const int l15 = lane & 15;
  const int l4 = lane >> 4;
  const int eblk = blockIdx.x * EPB;

  // ---- phase 0: metadata + bias staging + vectorized ea staging
  if (t < 32 * 4) rsh_sh[t >> 2][t & 3] = edge_rshs[(size_t)eblk * 4 + t];
  if (t < 32) {
    src_sh[t] = edge_index[NEDGE + eblk + t];
    slot_sh[t] = perm[eblk + t];
  }
  for (int i = t; i < 384; i += 256) b2s[i] = bf16b(b2[i]);
  if (t < 128) b1s[t] = bf16b(b1[t]);
  if (t < 128) {
    const int e = t >> 2, q = t & 3;
    const float4 v = *(const float4*)&edge_attr[(size_t)(eblk + e) * NBASIS + q * 4];
    u16x4 tmp;
    tmp[0] = bf16b(v.x); tmp[1] = bf16b(v.y); tmp[2] = bf16b(v.z); tmp[3] = bf16b(v.w);
    *(u16x4*)&sm.p1.ea[e * 48 + q * 4] = tmp;
  } else {
    const int idx = t - 128;           // 128 chunks × 8 shorts of K-pad
    const int e = idx >> 2, q = idx & 3;
    *(u16x8*)&sm.p1.ea[e * 48 + 16 + q * 8] = (u16x8){0, 0, 0, 0, 0, 0, 0, 0};
  }
  __syncthreads();

  // ---- phase 1: GEMM1 (H = silu(ea@W1+b1)) + sj/vd staging from bf16 sources
  {
    const int mt = w & 1, ch = w >> 1;
    const bf16x8 afrag = *(const bf16x8*)&sm.p1.ea[(mt * 16 + l15) * 48 + l4 * 8];
    #pragma unroll
    for (int nt = 0; nt < 4; ++nt) {
      const int ntg = ch * 4 + nt;
      const bf16x8 bfrag = *(const bf16x8*)&W1P[((size_t)ntg * 64 + lane) * 8];
      const int col = ntg * 16 + l15;
      const float bias = bf2f(b1s[col]);
      f32x4 d = {bias, bias, bias, bias};
      d = __builtin_amdgcn_mfma_f32_16x16x32_bf16(afrag, bfrag, d, 0, 0, 0);
      #pragma unroll
      for (int i = 0; i < 4; ++i) {
        const int e = mt * 16 + l4 * 4 + i;
        sm.p1.Hs[e * 136 + col] = bf16b(silu_f(d[i]));
      }
    }
  }
  // sj: straight u16x8 copy from x_s16
  #pragma unroll
  for (int p = 0; p < 2; ++p) {
    const int idx = p * 256 + t;
    const int e = idx >> 4, c8 = idx & 15;
    *(u16x8*)&sj[e][c8 * 8] =
        *(const u16x8*)&x_s16[(size_t)src_sh[e] * NS + c8 * 8];
  }
  // vd[e][u] = <v_j[u], r1> * inv_sqrt3 from bf16 planes
  #pragma unroll
  for (int p = 0; p < 8; ++p) {
    const int idx = p * 256 + t;
    const int e = idx >> 6, u = idx & 63;
    const size_t base = (size_t)src_sh[e] * NV + u;
    const float v0 = bf2f(xv16[base]);
    const float v1 = bf2f(xv16[VPLANE + base]);
    const float v2 = bf2f(xv16[2 * VPLANE + base]);
    const float dotv = fmaf(v0, rsh_sh[e][1], fmaf(v1, rsh_sh[e][2], v2 * rsh_sh[e][3]));
    vd[e][u] = bf16b(dotv * 0.5773502691896258f);
  }
  __syncthreads();

  // ---- phase 2: preload A-frags from Hs (then Hs is dead)
  bf16x8 afr[2][4];
  #pragma unroll
  for (int mt = 0; mt < 2; ++mt)
    #pragma unroll
    for (int k = 0; k < 4; ++k)
      afr[mt][k] = *(const bf16x8*)&sm.p1.Hs[(mt * 16 + l15) * 136 + k * 32 + l4 * 8];

  float r0a[2][4];
  #pragma unroll
  for (int mt = 0; mt < 2; ++mt)
    #pragma unroll
    for (int i = 0; i < 4; ++i) r0a[mt][i] = rsh_sh[mt * 16 + l4 * 4 + i][0];
  __syncthreads();   // everyone done reading Hs; msgb region now writable

  // ---- phase 3: GEMM2 + in-LDS epilogue
  #pragma unroll
  for (int nn = 0; nn < 6; ++nn) {
    const int nt = w * 6 + nn;
    bf16x8 bfr[4];
    #pragma unroll
    for (int k = 0; k < 4; ++k)
      bfr[k] = *(const bf16x8*)&W2P[(((size_t)nt * 4 + k) * 64 + lane) * 8];
    const int col = nt * 16 + l15;
    const float bias = bf2f(b2s[col]);
    f32x4 acc0 = {bias, bias, bias, bias}, acc1 = {bias, bias, bias, bias};
    #pragma unroll
    for (int k = 0; k < 4; ++k) {
      acc0 = __builtin_amdgcn_mfma_f32_16x16x32_bf16(afr[0][k], bfr[k], acc0, 0, 0, 0);
      acc1 = __builtin_amdgcn_mfma_f32_16x16x32_bf16(afr[1][k], bfr[k], acc1, 0, 0, 0);
    }
    if (col < NS) {
      #pragma unroll
      for (int mt = 0; mt < 2; ++mt)
        #pragma unroll
        for (int i = 0; i < 4; ++i) {
          const int e = mt * 16 + l4 * 4 + i;
          const float wv = mt ? acc1[i] : acc0[i];
          sm.msgb[e * 392 + col] = bf16b(wv * bf2f(sj[e][col]) * r0a[mt][i]);
        }
    } else if (col < NS + NV) {
      const int u = col - NS;
      #pragma unroll
      for (int mt = 0; mt < 2; ++mt)
        #pragma unroll
        for (int i = 0; i < 4; ++i) {
          const int e = mt * 16 + l4 * 4 + i;
          const float wv = mt ? acc1[i] : acc0[i];
          sm.msgb[e * 392 + col] = bf16b(wv * bf2f(vd[e][u]));
        }
    } else if (col < 2 * NS + NV) {
      const int sjc = col - (NS + NV);
      #pragma unroll
      for (int mt = 0; mt < 2; ++mt)
        #pragma unroll
        for (int i = 0; i < 4; ++i) {
          const int e = mt * 16 + l4 * 4 + i;
          const float wv = mt ? acc1[i] : acc0[i];
          sm.msgb[e * 392 + col] = bf16b(wv * bf2f(sj[e][sjc]));
        }
    } else {
      #pragma unroll
      for (int mt = 0; mt < 2; ++mt)
        #pragma unroll
        for (int i = 0; i < 4; ++i) {
          const int e = mt * 16 + l4 * 4 + i;
          const float wv = mt ? acc1[i] : acc0[i];
          sm.msgb[e * 392 + col] = bf16b(wv * r0a[mt][i]);
        }
    }
  }
  __syncthreads();

  // ---- phase 4: coalesced write-out, 768 B per edge row at its CSR slot
  #pragma unroll
  for (int p = 0; p < 6; ++p) {
    const int idx = p * 256 + t;
    const int e = idx / 48, c = idx - e * 48;
    const u16x8 vv = *(const u16x8*)&sm.msgb[e * 392 + c * 8];
    *(u16x8*)&msg[(size_t)slot_sh[e] * 384 + c * 8] = vv;
  }
}

// ===== node_gather: 4 role-waves, batch-16/8 unrolled loads ===================
__global__ __launch_bounds__(256) void node_gather(
    const unsigned short* __restrict__ msg, const int* __restrict__ row_start,
    const float4* __restrict__ meta, const unsigned short* __restrict__ xv16,
    unsigned short* __restrict__ gs16, unsigned short* __restrict__ gv16) {
  const int n = blockIdx.x;
  const int t = threadIdx.x;
  const int role = t >> 6, ln = t & 63;
  const int beg = row_start[n], end = row_start[n + 1];

  float a0 = 0.f, a1 = 0.f, a2 = 0.f;

  if (role == 0) {
    const unsigned short* mp = msg + (size_t)beg * 384;
    int i = beg;
    for (; i + 16 <= end; i += 16, mp += 6144) {
      unsigned int pr[16]; unsigned short v2[16];
      #pragma unroll
      for (int u = 0; u < 16; ++u) {
        pr[u] = *(const unsigned int*)(mp + u * 384 + 2 * ln);
        v2[u] = mp[u * 384 + 128 + ln];
      }
      #pragma unroll
      for (int u = 0; u < 16; ++u) {
        a0 += __uint_as_float(pr[u] << 16);
        a1 += __uint_as_float(pr[u] & 0xffff0000u);
        a2 += bf2f(v2[u]);
      }
    }
    for (; i + 8 <= end; i += 8, mp += 3072) {
      unsigned int pr[8]; unsigned short v2[8];
      #pragma unroll
      for (int u = 0; u < 8; ++u) {
        pr[u] = *(const unsigned int*)(mp + u * 384 + 2 * ln);
        v2[u] = mp[u * 384 + 128 + ln];
      }
      #pragma unroll
      for (int u = 0; u < 8; ++u) {
        a0 += __uint_as_float(pr[u] << 16);
        a1 += __uint_as_float(pr[u] & 0xffff0000u);
        a2 += bf2f(v2[u]);
      }
    }
    for (; i < end; ++i, mp += 384) {
      const unsigned int p = *(const unsigned int*)(mp + 2 * ln);
      a0 += __uint_as_float(p << 16);
      a1 += __uint_as_float(p & 0xffff0000u);
      a2 += bf2f(mp[128 + ln]);
    }
    gs16[(size_t)n * 192 + 2 * ln]     = bf16b(silu_f(a0));
    gs16[(size_t)n * 192 + 2 * ln + 1] = bf16b(silu_f(a1));
    gs16[(size_t)n * 192 + 128 + ln]   = bf16b(silu_f(a2));
  } else {
    if (role < 3) {
      const unsigned short* mp = msg + (size_t)beg * 384 + 192 + (role - 1) * 64 + ln;
      int i = beg;
      for (; i + 16 <= end; i += 16, mp += 6144) {
        float4 mt[16]; unsigned short v[16];
        #pragma unroll
        for (int u = 0; u < 16; ++u) { mt[u] = meta[i + u]; v[u] = mp[u * 384]; }
        #pragma unroll
        for (int u = 0; u < 16; ++u) {
          const float m = bf2f(v[u]);
          a0 = fmaf(m, mt[u].y, a0);
          a1 = fmaf(m, mt[u].z, a1);
          a2 = fmaf(m, mt[u].w, a2);
        }
      }
      for (; i + 8 <= end; i += 8, mp += 3072) {
        float4 mt[8]; unsigned short v[8];
        #pragma unroll
        for (int u = 0; u < 8; ++u) { mt[u] = meta[i + u]; v[u] = mp[u * 384]; }
        #pragma unroll
        for (int u = 0; u < 8; ++u) {
          const float m = bf2f(v[u]);
          a0 = fmaf(m, mt[u].y, a0);
          a1 = fmaf(m, mt[u].z, a1);
          a2 = fmaf(m, mt[u].w, a2);
        }
      }
      for (; i < end; ++i, mp += 384) {
        const float4 mt = meta[i];
        const float m = bf2f(mp[0]);
        a0 = fmaf(m, mt.y, a0); a1 = fmaf(m, mt.z, a1); a2 = fmaf(m, mt.w, a2);
      }
    } else {
      const unsigned short* mp = msg + (size_t)beg * 384 + 320 + ln;
      int i = beg;
      for (; i + 8 <= end; i += 8, mp += 3072) {
        float4 mt[8]; unsigned short v[8];
        #pragma unroll
        for (int u = 0; u < 8; ++u) { mt[u] = meta[i + u]; v[u] = mp[u * 384]; }
        unsigned short x0[8], x1[8], x2[8];
        #pragma unroll
        for (int u = 0; u < 8; ++u) {
          const size_t base = (size_t)__float_as_int(mt[u].x) * NV + ln;
          x0[u] = xv16[base]; x1[u] = xv16[VPLANE + base]; x2[u] = xv16[2 * VPLANE + base];
        }
        #pragma unroll
        for (int u = 0; u < 8; ++u) {
          const float m = bf2f(v[u]);
          a0 = fmaf(m, bf2f(x0[u]), a0);
          a1 = fmaf(m, bf2f(x1[u]), a1);
          a2 = fmaf(m, bf2f(x2[u]), a2);
        }
      }
      for (; i < end; ++i, mp += 384) {
        const float4 mt = meta[i];
        const float m = bf2f(mp[0]);
        const size_t base = (size_t)__float_as_int(mt.x) * NV + ln;
        a0 = fmaf(m, bf2f(xv16[base]), a0);
        a1 = fmaf(m, bf2f(xv16[VPLANE + base]), a1);
        a2 = fmaf(m, bf2f(xv16[2 * VPLANE + base]), a2);
      }
    }
    const float nrm = sqrtf(fmaf(a0, a0, fmaf(a1, a1, a2 * a2)) + 1e-12f);
    const float sg = 1.f / (1.f + __expf(-nrm));
    const int u = (role < 3) ? (role - 1) * 64 + ln : 128 + ln;
    gv16[(size_t)0 * GVPLANE + (size_t)n * 192 + u] = bf16b(a0 * sg);
    gv16[(size_t)1 * GVPLANE + (size_t)n * 192 + u] = bf16b(a1 * sg);
    gv16[(size_t)2 * GVPLANE + (size_t)n * 192 + u] = bf16b(a2 * sg);
  }
}

// ===== node_post_mfma: 32 nodes/block; SC folded into packed weights ==========
__global__ __launch_bounds__(256) void node_post_mfma(
    const unsigned short* __restrict__ gs16, const unsigned short* __restrict__ gv16,
    const unsigned short* __restrict__ WqsP, const unsigned short* __restrict__ WqvP,
    const float* __restrict__ x_s, const float* __restrict__ x_v,
    float* __restrict__ out) {
  __shared__ __align__(16) unsigned short gsA[32 * 200];
  __shared__ __align__(16) unsigned short gvA[3][32 * 200];
  const int n0 = blockIdx.x * 32;
  const int t = threadIdx.x;
  const int lane = t & 63;
  const int w = t >> 6;
  const int l15 = lane & 15;
  const int l4 = lane >> 4;

  {
    const unsigned short* sp = gs16 + (size_t)n0 * 192;
    for (int idx = t; idx < 768; idx += 256) {
      const int row = idx / 24, ch = idx - row * 24;
      *(u16x8*)&gsA[row * 200 + ch * 8] = *(const u16x8*)&sp[row * 192 + ch * 8];
    }
    #pragma unroll
    for (int c = 0; c < 3; ++c) {
      const unsigned short* vp = gv16 + (size_t)c * GVPLANE + (size_t)n0 * 192;
      for (int idx = t; idx < 768; idx += 256) {
        const int row = idx / 24, ch = idx - row * 24;
        *(u16x8*)&gvA[c][row * 200 + ch * 8] = *(const u16x8*)&vp[row * 192 + ch * 8];
      }
    }
  }
  __syncthreads();

  f32x4 accS[2][2];
  f32x4 accV[3][2];
  #pragma unroll
  for (int j = 0; j < 2; ++j)
    #pragma unroll
    for (int mt = 0; mt < 2; ++mt) accS[j][mt] = (f32x4){0.f, 0.f, 0.f, 0.f};
  #pragma unroll
  for (int c = 0; c < 3; ++c)
    #pragma unroll
    for (int mt = 0; mt < 2; ++mt) accV[c][mt] = (f32x4){0.f, 0.f, 0.f, 0.f};

  #pragma unroll
  for (int kc = 0; kc < 6; ++kc) {
    bf16x8 aS[2], aV[3][2];
    #pragma unroll
    for (int mt = 0; mt < 2; ++mt)
      aS[mt] = *(const bf16x8*)&gsA[(mt * 16 + l15) * 200 + kc * 32 + l4 * 8];
    #pragma unroll
    for (int c = 0; c < 3; ++c)
      #pragma unroll
      for (int mt = 0; mt < 2; ++mt)
        aV[c][mt] = *(const bf16x8*)&gvA[c][(mt * 16 + l15) * 200 + kc * 32 + l4 * 8];
    const bf16x8 bS0 = *(const bf16x8*)&WqsP[(((size_t)(w * 2 + 0) * 6 + kc) * 64 + lane) * 8];
    const bf16x8 bS1 = *(const bf16x8*)&WqsP[(((size_t)(w * 2 + 1) * 6 + kc) * 64 + lane) * 8];
    const bf16x8 bV  = *(const bf16x8*)&WqvP[(((size_t)w * 6 + kc) * 64 + lane) * 8];
    #pragma unroll
    for (int mt = 0; mt < 2; ++mt) {
      accS[0][mt] = __builtin_amdgcn_mfma_f32_16x16x32_bf16(aS[mt], bS0, accS[0][mt], 0, 0, 0);
      accS[1][mt] = __builtin_amdgcn_mfma_f32_16x16x32_bf16(aS[mt], bS1, accS[1][mt], 0, 0, 0);
    }
    #pragma unroll
    for (int c = 0; c < 3; ++c)
      #pragma unroll
      for (int mt = 0; mt < 2; ++mt)
        accV[c][mt] = __builtin_amdgcn_mfma_f32_16x16x32_bf16(aV[c][mt], bV, accV[c][mt], 0, 0, 0);
  }

  #pragma unroll
  for (int j = 0; j < 2; ++j) {
    const int col = (w * 2 + j) * 16 + l15;
    #pragma unroll
    for (int mt = 0; mt < 2; ++mt)
      #pragma unroll
      for (int i = 0; i < 4; ++i) {
        const int row = n0 + mt * 16 + l4 * 4 + i;
        out[(size_t)row * 320 + col] =
            x_s[(size_t)row * NS + col] + accS[j][mt][i];
      }
  }
  {
    const int vch = w * 16 + l15;
    #pragma unroll
    for (int mt = 0; mt < 2; ++mt)
      #pragma unroll
      for (int i = 0; i < 4; ++i) {
        const int row = n0 + mt * 16 + l4 * 4 + i;
        const float* xvp = x_v + (size_t)row * (NV * 3) + vch * 3;
        float o0 = xvp[0] + accV[0][mt][i];
        float o1 = xvp[1] + accV[1][mt][i];
        float o2 = xvp[2] + accV[2][mt][i];
        float* op = out + (size_t)row * 320 + NS + vch * 3;
        op[0] = o0; op[1] = o1; op[2] = o2;
      }
  }
}

extern "C" void kernel_launch(void* const* d_in, const int* in_sizes, int n_in,
                              void* d_out, int out_size, void* d_ws, size_t ws_size,
                              hipStream_t stream) {
  const float* node_feat = (const float*)d_in[0];
  const float* edge_attr = (const float*)d_in[1];
  const float* edge_rshs = (const float*)d_in[2];
  const int*   edge_index = (const int*)d_in[3];
  const float* Wps = (const float*)d_in[4];
  const float* bps = (const float*)d_in[5];
  const float* Wpv = (const float*)d_in[6];
  const float* W1  = (const float*)d_in[7];
  const float* b1  = (const float*)d_in[8];
  const float* W2  = (const float*)d_in[9];
  const float* b2  = (const float*)d_in[10];
  const float* Wqs = (const float*)d_in[11];
  const float* Wqv = (const float*)d_in[12];
  float* out = (float*)d_out;

  float* x_s = (float*)d_ws;                                            // 16000*128 f32
  float* x_v = x_s + (size_t)NNODE * NS;                                // 16000*192 f32
  unsigned short* msg = (unsigned short*)(x_v + (size_t)NNODE * NV * 3);// 256000*384 bf16
  unsigned short* W1P = msg + (size_t)NEDGE * 384;                      // 4096
  unsigned short* W2P = W1P + 8 * 64 * 8;                               // 49152
  unsigned short* WqsP = W2P + 24 * 4 * 64 * 8;                         // 24576
  unsigned short* WqvP = WqsP + 8 * 6 * 64 * 8;                         // 12288
  unsigned short* WpsP = WqvP + 4 * 6 * 64 * 8;                         // 16384
  unsigned short* WpvP = WpsP + 8 * 4 * 64 * 8;                         // 4096
  unsigned short* x_s16 = WpvP + 4 * 2 * 64 * 8;                        // 2,048,000
  unsigned short* xv16 = x_s16 + (size_t)NNODE * NS;                    // 3,072,000
  unsigned short* gs16 = xv16 + (size_t)3 * VPLANE;                     // 3,072,000
  unsigned short* gv16 = gs16 + (size_t)NNODE * 192;                    // 9,216,000
  float4* meta = (float4*)(gv16 + (size_t)3 * GVPLANE);                 // NEDGE float4
  int* row_start = (int*)(meta + NEDGE);                                // NNODE+1
  int* cursor = row_start + (NNODE + 1);                                // NNODE
  int* perm = cursor + NNODE;                                           // NEDGE

  pack_weights<<<192, 256, 0, stream>>>(W1, W2, Wqs, Wqv, Wps, Wpv,
      W1P, W2P, WqsP, WqvP, WpsP, WpvP, cursor);
  node_pre_mfma<<<NNODE / 32, 256, 0, stream>>>(node_feat, bps, WpsP, WpvP,
      edge_index, cursor, x_s, x_v, x_s16, xv16);
  scan_kernel<<<1, 256, 0, stream>>>(cursor, row_start, cursor);
  scatter_kernel<<<(NEDGE + 255) / 256, 256, 0, stream>>>(edge_index, edge_rshs,
      cursor, perm, meta);
  edge_mlp_mfma<<<NEDGE / EPB, 256, 0, stream>>>(edge_attr, edge_rshs, edge_index,
      perm, W1P, b1, W2P, b2, x_s16, xv16, msg);
  node_gather<<<NNODE, 256, 0, stream>>>(msg, row_start, meta, xv16, gs16, gv16);
  node_post_mfma<<<NNODE / 32, 256, 0, stream>>>(gs16, gv16, WqsP, WqvP,
      x_s, x_v, out);
}

// Round 18
// 242.238 us; speedup vs baseline: 1.1957x; 1.0306x over previous
//
#include <hip/hip_runtime.h>
#include <hip/hip_bf16.h>

#define NS 128
#define NV 64
#define TPC 192
#define NBASIS 16
#define HID 128
#define WOUT 384
#define NNODE 16000
#define NEDGE 256000
#define EPB 32
#define GVPLANE 3072000   // 16000*192
#define VPLANE  1024000   // 16000*64

typedef __attribute__((ext_vector_type(8))) short bf16x8;
typedef __attribute__((ext_vector_type(8))) unsigned short u16x8;
typedef __attribute__((ext_vector_type(4))) unsigned short u16x4;
typedef __attribute__((ext_vector_type(4))) float f32x4;

__device__ __forceinline__ float silu_f(float x) { return x / (1.0f + __expf(-x)); }
__device__ __forceinline__ unsigned short bf16b(float x) {
  __hip_bfloat16 h = __float2bfloat16(x);
  return *reinterpret_cast<unsigned short*>(&h);
}
__device__ __forceinline__ float bf2f(unsigned short u) {
  return __uint_as_float(((unsigned)u) << 16);
}

// ---- pack W1/W2/Wqs/Wqv/Wps/Wpv into MFMA B-fragment order (bf16, scales folded)
__global__ __launch_bounds__(256) void pack_weights(
    const float* __restrict__ W1, const float* __restrict__ W2,
    const float* __restrict__ Wqs, const float* __restrict__ Wqv,
    const float* __restrict__ Wps, const float* __restrict__ Wpv,
    unsigned short* __restrict__ W1P, unsigned short* __restrict__ W2P,
    unsigned short* __restrict__ WqsP, unsigned short* __restrict__ WqvP,
    unsigned short* __restrict__ WpsP, unsigned short* __restrict__ WpvP,
    int* __restrict__ cursor) {
  const int id = blockIdx.x * 256 + threadIdx.x;
  const int j = id & 7, lane = (id >> 3) & 63;
  const int kj = (lane >> 4) * 8 + j;       // k-offset within 32-chunk
  const int nc = lane & 15;                 // col within 16-tile
  const float SC = 0.07216878364870323f;
  if (id < NNODE) cursor[id] = 0;           // replaces hipMemsetAsync
  if (id < 24 * 4 * 64 * 8) {               // W2P[nt24][kc4][lane][8]
    const int kc = (id >> 9) & 3, nt = id >> 11;
    W2P[id] = bf16b(W2[(kc * 32 + kj) * WOUT + nt * 16 + nc]);
  }
  if (id < 8 * 64 * 8) {                    // W1P[nt8][lane][8] (K=16 padded to 32)
    const int nt = id >> 9;
    W1P[id] = (kj < NBASIS) ? bf16b(W1[kj * HID + nt * 16 + nc]) : (unsigned short)0;
  }
  if (id < 8 * 6 * 64 * 8) {                // WqsP[nt8][kc6][lane][8], SC folded
    const int kc = (id >> 9) % 6, nt = id / (6 * 512);
    WqsP[id] = bf16b(Wqs[(kc * 32 + kj) * NS + nt * 16 + nc] * SC);
  }
  if (id < 4 * 6 * 64 * 8) {                // WqvP[nt4][kc6][lane][8], SC folded
    const int kc = (id >> 9) % 6, nt = id / (6 * 512);
    WqvP[id] = bf16b(Wqv[(kc * 32 + kj) * NV + nt * 16 + nc] * SC);
  }
  if (id < 8 * 4 * 64 * 8) {                // WpsP[nt8][kc4][lane][8], 1/sqrt(128) folded
    const int kc = (id >> 9) & 3, nt = id >> 11;
    WpsP[id] = bf16b(Wps[(kc * 32 + kj) * NS + nt * 16 + nc] * 0.08838834764831845f);
  }
  if (id < 4 * 2 * 64 * 8) {                // WpvP[nt4][kc2][lane][8], 1/8 folded
    const int kc = (id >> 9) & 1, nt = id >> 10;
    WpvP[id] = bf16b(Wpv[(kc * 32 + kj) * NV + nt * 16 + nc] * 0.125f);
  }
}

// ====== node_pre_mfma: 32 nodes/block; bf16-only outputs + edge hist ==========
__global__ __launch_bounds__(256) void node_pre_mfma(
    const float* __restrict__ node_feat, const float* __restrict__ bps,
    const unsigned short* __restrict__ WpsP, const unsigned short* __restrict__ WpvP,
    const int* __restrict__ edge_index, int* __restrict__ cnt,
    unsigned short* __restrict__ x_s16, unsigned short* __restrict__ xv16) {
  __shared__ __align__(16) unsigned short as_[32 * 136];   // s-part rows, bf16
  __shared__ __align__(16) unsigned short avp[3][32 * 72]; // v planes by c, bf16
  const int n0 = blockIdx.x * 32;
  const int t = threadIdx.x;
  const int lane = t & 63;
  const int w = t >> 6;
  const int l15 = lane & 15;
  const int l4 = lane >> 4;

  // stage s-part (coalesced float4 -> bf16)
  #pragma unroll
  for (int p = 0; p < 4; ++p) {
    const int idx = p * 256 + t;
    const int r = idx >> 5, c4 = idx & 31;
    const float4 v = *(const float4*)&node_feat[(size_t)(n0 + r) * 320 + c4 * 4];
    u16x4 tmp;
    tmp[0] = bf16b(v.x); tmp[1] = bf16b(v.y); tmp[2] = bf16b(v.z); tmp[3] = bf16b(v.w);
    *(u16x4*)&as_[r * 136 + c4 * 4] = tmp;
  }
  // stage v-part into 3 c-planes
  #pragma unroll
  for (int p = 0; p < 8; ++p) {
    const int idx = p * 256 + t;
    const int r = idx >> 6, u = idx & 63;
    const float* vp = &node_feat[(size_t)(n0 + r) * 320 + 128 + u * 3];
    avp[0][r * 72 + u] = bf16b(vp[0]);
    avp[1][r * 72 + u] = bf16b(vp[1]);
    avp[2][r * 72 + u] = bf16b(vp[2]);
  }
  __syncthreads();

  f32x4 accS[2][2];
  #pragma unroll
  for (int jj = 0; jj < 2; ++jj) {
    const float b = bps[(w * 2 + jj) * 16 + l15];
    #pragma unroll
    for (int mt = 0; mt < 2; ++mt) accS[jj][mt] = (f32x4){b, b, b, b};
  }
  f32x4 accV[3][2];
  #pragma unroll
  for (int c = 0; c < 3; ++c)
    #pragma unroll
    for (int mt = 0; mt < 2; ++mt) accV[c][mt] = (f32x4){0.f, 0.f, 0.f, 0.f};

  #pragma unroll
  for (int kc = 0; kc < 4; ++kc) {
    bf16x8 aS[2];
    #pragma unroll
    for (int mt = 0; mt < 2; ++mt)
      aS[mt] = *(const bf16x8*)&as_[(mt * 16 + l15) * 136 + kc * 32 + l4 * 8];
    const bf16x8 bS0 = *(const bf16x8*)&WpsP[(((size_t)(w * 2 + 0) * 4 + kc) * 64 + lane) * 8];
    const bf16x8 bS1 = *(const bf16x8*)&WpsP[(((size_t)(w * 2 + 1) * 4 + kc) * 64 + lane) * 8];
    #pragma unroll
    for (int mt = 0; mt < 2; ++mt) {
      accS[0][mt] = __builtin_amdgcn_mfma_f32_16x16x32_bf16(aS[mt], bS0, accS[0][mt], 0, 0, 0);
      accS[1][mt] = __builtin_amdgcn_mfma_f32_16x16x32_bf16(aS[mt], bS1, accS[1][mt], 0, 0, 0);
    }
  }
  #pragma unroll
  for (int kc = 0; kc < 2; ++kc) {
    const bf16x8 bV = *(const bf16x8*)&WpvP[(((size_t)w * 2 + kc) * 64 + lane) * 8];
    #pragma unroll
    for (int c = 0; c < 3; ++c) {
      bf16x8 aV[2];
      #pragma unroll
      for (int mt = 0; mt < 2; ++mt)
        aV[mt] = *(const bf16x8*)&avp[c][(mt * 16 + l15) * 72 + kc * 32 + l4 * 8];
      #pragma unroll
      for (int mt = 0; mt < 2; ++mt)
        accV[c][mt] = __builtin_amdgcn_mfma_f32_16x16x32_bf16(aV[mt], bV, accV[c][mt], 0, 0, 0);
    }
  }

  #pragma unroll
  for (int jj = 0; jj < 2; ++jj) {
    const int col = (w * 2 + jj) * 16 + l15;
    #pragma unroll
    for (int mt = 0; mt < 2; ++mt)
      #pragma unroll
      for (int i = 0; i < 4; ++i) {
        const int row = n0 + mt * 16 + l4 * 4 + i;
        x_s16[(size_t)row * NS + col] = bf16b(accS[jj][mt][i]);
      }
  }
  {
    const int vch = w * 16 + l15;
    #pragma unroll
    for (int mt = 0; mt < 2; ++mt)
      #pragma unroll
      for (int i = 0; i < 4; ++i) {
        const int row = n0 + mt * 16 + l4 * 4 + i;
        xv16[(size_t)0 * VPLANE + (size_t)row * NV + vch] = bf16b(accV[0][mt][i]);
        xv16[(size_t)1 * VPLANE + (size_t)row * NV + vch] = bf16b(accV[1][mt][i]);
        xv16[(size_t)2 * VPLANE + (size_t)row * NV + vch] = bf16b(accV[2][mt][i]);
      }
  }

  // folded edge histogram (grid-stride; overlaps with other blocks' GEMMs)
  for (int e = blockIdx.x * 256 + t; e < NEDGE; e += gridDim.x * 256)
    atomicAdd(&cnt[edge_index[e]], 1);
}

// ================= CSR scan =================
__global__ __launch_bounds__(256) void scan_kernel(
    const int* __restrict__ cnt, int* __restrict__ row_start, int* __restrict__ cursor) {
  __shared__ int part[256];
  const int t = threadIdx.x;
  const int base = t * 63;
  int s = 0;
  for (int i = 0; i < 63; ++i) {
    int idx = base + i;
    if (idx < NNODE) s += cnt[idx];
  }
  part[t] = s;
  __syncthreads();
  if (t == 0) {
    int run = 0;
    for (int i = 0; i < 256; ++i) { int x = part[i]; part[i] = run; run += x; }
  }
  __syncthreads();
  int run = part[t];
  for (int i = 0; i < 63; ++i) {
    int idx = base + i;
    if (idx < NNODE) {
      int c = cnt[idx];   // read before overwrite (cnt aliases cursor)
      row_start[idx] = run;
      cursor[idx] = run;
      run += c;
    }
  }
  if (t == 255) row_start[NNODE] = run;
}

// scatter: assign CSR slot, record perm (edge->slot) and per-slot meta {src, r1}
__global__ void scatter_kernel(const int* __restrict__ ei,
                               const float* __restrict__ edge_rshs,
                               int* __restrict__ cursor, int* __restrict__ perm,
                               float4* __restrict__ meta) {
  int e = blockIdx.x * 256 + threadIdx.x;
  if (e < NEDGE) {
    int p = atomicAdd(&cursor[ei[e]], 1);
    perm[e] = p;
    float4 m;
    m.x = __int_as_float(ei[NEDGE + e]);
    m.y = edge_rshs[e * 4 + 1];
    m.z = edge_rshs[e * 4 + 2];
    m.w = edge_rshs[e * 4 + 3];
    meta[p] = m;
  }
}

// ================= edge MLP via MFMA -> bf16 messages at CSR slots ============
__global__ __launch_bounds__(256) void edge_mlp_mfma(
    const float* __restrict__ edge_attr, const float* __restrict__ edge_rshs,
    const int* __restrict__ edge_index, const int* __restrict__ perm,
    const unsigned short* __restrict__ W1P, const float* __restrict__ b1,
    const unsigned short* __restrict__ W2P, const float* __restrict__ b2,
    const unsigned short* __restrict__ x_s16, const unsigned short* __restrict__ xv16,
    unsigned short* __restrict__ msg) {
  union SMU {
    struct { unsigned short ea[32 * 48]; unsigned short Hs[32 * 136]; } p1;
    unsigned short msgb[32 * 392];
  };
  __shared__ __align__(16) SMU sm;
  __shared__ __align__(16) unsigned short sj[32][136];
  __shared__ __align__(16) unsigned short vd[32][72];
  __shared__ unsigned short b2s[384];
  __shared__ unsigned short b1s[128];
  __shared__ int src_sh[32];
  __shared__ int slot_sh[32];
  __shared__ float rsh_sh[32][4];
  const int t = threadIdx.x;
  const int lane = t & 63;
  const int w = t >> 6;
  const int l15 = lane & 15;
  const int l4 = lane >> 4;
  const int eblk = blockIdx.x * EPB;

  // ---- phase 0: metadata + bias staging + vectorized ea staging
  if (t < 32 * 4) rsh_sh[t >> 2][t & 3] = edge_rshs[(size_t)eblk * 4 + t];
  if (t < 32) {
    src_sh[t] = edge_index[NEDGE + eblk + t];
    slot_sh[t] = perm[eblk + t];
  }
  for (int i = t; i < 384; i += 256) b2s[i] = bf16b(b2[i]);
  if (t < 128) b1s[t] = bf16b(b1[t]);
  if (t < 128) {
    const int e = t >> 2, q = t & 3;
    const float4 v = *(const float4*)&edge_attr[(size_t)(eblk + e) * NBASIS + q * 4];
    u16x4 tmp;
    tmp[0] = bf16b(v.x); tmp[1] = bf16b(v.y); tmp[2] = bf16b(v.z); tmp[3] = bf16b(v.w);
    *(u16x4*)&sm.p1.ea[e * 48 + q * 4] = tmp;
  } else {
    const int idx = t - 128;           // 128 chunks × 8 shorts of K-pad
    const int e = idx >> 2, q = idx & 3;
    *(u16x8*)&sm.p1.ea[e * 48 + 16 + q * 8] = (u16x8){0, 0, 0, 0, 0, 0, 0, 0};
  }
  __syncthreads();

  // ---- phase 1: GEMM1 (H = silu(ea@W1+b1)) + sj/vd staging from bf16 sources
  {
    const int mt = w & 1, ch = w >> 1;
    const bf16x8 afrag = *(const bf16x8*)&sm.p1.ea[(mt * 16 + l15) * 48 + l4 * 8];
    #pragma unroll
    for (int nt = 0; nt < 4; ++nt) {
      const int ntg = ch * 4 + nt;
      const bf16x8 bfrag = *(const bf16x8*)&W1P[((size_t)ntg * 64 + lane) * 8];
      const int col = ntg * 16 + l15;
      const float bias = bf2f(b1s[col]);
      f32x4 d = {bias, bias, bias, bias};
      d = __builtin_amdgcn_mfma_f32_16x16x32_bf16(afrag, bfrag, d, 0, 0, 0);
      #pragma unroll
      for (int i = 0; i < 4; ++i) {
        const int e = mt * 16 + l4 * 4 + i;
        sm.p1.Hs[e * 136 + col] = bf16b(silu_f(d[i]));
      }
    }
  }
  // sj: straight u16x8 copy from x_s16
  #pragma unroll
  for (int p = 0; p < 2; ++p) {
    const int idx = p * 256 + t;
    const int e = idx >> 4, c8 = idx & 15;
    *(u16x8*)&sj[e][c8 * 8] =
        *(const u16x8*)&x_s16[(size_t)src_sh[e] * NS + c8 * 8];
  }
  // vd[e][u] = <v_j[u], r1> * inv_sqrt3 from bf16 planes
  #pragma unroll
  for (int p = 0; p < 8; ++p) {
    const int idx = p * 256 + t;
    const int e = idx >> 6, u = idx & 63;
    const size_t base = (size_t)src_sh[e] * NV + u;
    const float v0 = bf2f(xv16[base]);
    const float v1 = bf2f(xv16[VPLANE + base]);
    const float v2 = bf2f(xv16[2 * VPLANE + base]);
    const float dotv = fmaf(v0, rsh_sh[e][1], fmaf(v1, rsh_sh[e][2], v2 * rsh_sh[e][3]));
    vd[e][u] = bf16b(dotv * 0.5773502691896258f);
  }
  __syncthreads();

  // ---- phase 2: preload A-frags from Hs (then Hs is dead)
  bf16x8 afr[2][4];
  #pragma unroll
  for (int mt = 0; mt < 2; ++mt)
    #pragma unroll
    for (int k = 0; k < 4; ++k)
      afr[mt][k] = *(const bf16x8*)&sm.p1.Hs[(mt * 16 + l15) * 136 + k * 32 + l4 * 8];

  float r0a[2][4];
  #pragma unroll
  for (int mt = 0; mt < 2; ++mt)
    #pragma unroll
    for (int i = 0; i < 4; ++i) r0a[mt][i] = rsh_sh[mt * 16 + l4 * 4 + i][0];
  __syncthreads();   // everyone done reading Hs; msgb region now writable

  // ---- phase 3: GEMM2 + in-LDS epilogue
  #pragma unroll
  for (int nn = 0; nn < 6; ++nn) {
    const int nt = w * 6 + nn;
    bf16x8 bfr[4];
    #pragma unroll
    for (int k = 0; k < 4; ++k)
      bfr[k] = *(const bf16x8*)&W2P[(((size_t)nt * 4 + k) * 64 + lane) * 8];
    const int col = nt * 16 + l15;
    const float bias = bf2f(b2s[col]);
    f32x4 acc0 = {bias, bias, bias, bias}, acc1 = {bias, bias, bias, bias};
    #pragma unroll
    for (int k = 0; k < 4; ++k) {
      acc0 = __builtin_amdgcn_mfma_f32_16x16x32_bf16(afr[0][k], bfr[k], acc0, 0, 0, 0);
      acc1 = __builtin_amdgcn_mfma_f32_16x16x32_bf16(afr[1][k], bfr[k], acc1, 0, 0, 0);
    }
    if (col < NS) {
      #pragma unroll
      for (int mt = 0; mt < 2; ++mt)
        #pragma unroll
        for (int i = 0; i < 4; ++i) {
          const int e = mt * 16 + l4 * 4 + i;
          const float wv = mt ? acc1[i] : acc0[i];
          sm.msgb[e * 392 + col] = bf16b(wv * bf2f(sj[e][col]) * r0a[mt][i]);
        }
    } else if (col < NS + NV) {
      const int u = col - NS;
      #pragma unroll
      for (int mt = 0; mt < 2; ++mt)
        #pragma unroll
        for (int i = 0; i < 4; ++i) {
          const int e = mt * 16 + l4 * 4 + i;
          const float wv = mt ? acc1[i] : acc0[i];
          sm.msgb[e * 392 + col] = bf16b(wv * bf2f(vd[e][u]));
        }
    } else if (col < 2 * NS + NV) {
      const int sjc = col - (NS + NV);
      #pragma unroll
      for (int mt = 0; mt < 2; ++mt)
        #pragma unroll
        for (int i = 0; i < 4; ++i) {
          const int e = mt * 16 + l4 * 4 + i;
          const float wv = mt ? acc1[i] : acc0[i];
          sm.msgb[e * 392 + col] = bf16b(wv * bf2f(sj[e][sjc]));
        }
    } else {
      #pragma unroll
      for (int mt = 0; mt < 2; ++mt)
        #pragma unroll
        for (int i = 0; i < 4; ++i) {
          const int e = mt * 16 + l4 * 4 + i;
          const float wv = mt ? acc1[i] : acc0[i];
          sm.msgb[e * 392 + col] = bf16b(wv * r0a[mt][i]);
        }
    }
  }
  __syncthreads();

  // ---- phase 4: coalesced write-out, 768 B per edge row at its CSR slot
  #pragma unroll
  for (int p = 0; p < 6; ++p) {
    const int idx = p * 256 + t;
    const int e = idx / 48, c = idx - e * 48;
    const u16x8 vv = *(const u16x8*)&sm.msgb[e * 392 + c * 8];
    *(u16x8*)&msg[(size_t)slot_sh[e] * 384 + c * 8] = vv;
  }
}

// ===== node_gather: 4 role-waves, batch-16/8 unrolled loads ===================
__global__ __launch_bounds__(256) void node_gather(
    const unsigned short* __restrict__ msg, const int* __restrict__ row_start,
    const float4* __restrict__ meta, const unsigned short* __restrict__ xv16,
    unsigned short* __restrict__ gs16, unsigned short* __restrict__ gv16) {
  const int n = blockIdx.x;
  const int t = threadIdx.x;
  const int role = t >> 6, ln = t & 63;
  const int beg = row_start[n], end = row_start[n + 1];

  float a0 = 0.f, a1 = 0.f, a2 = 0.f;

  if (role == 0) {
    const unsigned short* mp = msg + (size_t)beg * 384;
    int i = beg;
    for (; i + 16 <= end; i += 16, mp += 6144) {
      unsigned int pr[16]; unsigned short v2[16];
      #pragma unroll
      for (int u = 0; u < 16; ++u) {
        pr[u] = *(const unsigned int*)(mp + u * 384 + 2 * ln);
        v2[u] = mp[u * 384 + 128 + ln];
      }
      #pragma unroll
      for (int u = 0; u < 16; ++u) {
        a0 += __uint_as_float(pr[u] << 16);
        a1 += __uint_as_float(pr[u] & 0xffff0000u);
        a2 += bf2f(v2[u]);
      }
    }
    for (; i + 8 <= end; i += 8, mp += 3072) {
      unsigned int pr[8]; unsigned short v2[8];
      #pragma unroll
      for (int u = 0; u < 8; ++u) {
        pr[u] = *(const unsigned int*)(mp + u * 384 + 2 * ln);
        v2[u] = mp[u * 384 + 128 + ln];
      }
      #pragma unroll
      for (int u = 0; u < 8; ++u) {
        a0 += __uint_as_float(pr[u] << 16);
        a1 += __uint_as_float(pr[u] & 0xffff0000u);
        a2 += bf2f(v2[u]);
      }
    }
    for (; i < end; ++i, mp += 384) {
      const unsigned int p = *(const unsigned int*)(mp + 2 * ln);
      a0 += __uint_as_float(p << 16);
      a1 += __uint_as_float(p & 0xffff0000u);
      a2 += bf2f(mp[128 + ln]);
    }
    gs16[(size_t)n * 192 + 2 * ln]     = bf16b(silu_f(a0));
    gs16[(size_t)n * 192 + 2 * ln + 1] = bf16b(silu_f(a1));
    gs16[(size_t)n * 192 + 128 + ln]   = bf16b(silu_f(a2));
  } else {
    if (role < 3) {
      const unsigned short* mp = msg + (size_t)beg * 384 + 192 + (role - 1) * 64 + ln;
      int i = beg;
      for (; i + 16 <= end; i += 16, mp += 6144) {
        float4 mt[16]; unsigned short v[16];
        #pragma unroll
        for (int u = 0; u < 16; ++u) { mt[u] = meta[i + u]; v[u] = mp[u * 384]; }
        #pragma unroll
        for (int u = 0; u < 16; ++u) {
          const float m = bf2f(v[u]);
          a0 = fmaf(m, mt[u].y, a0);
          a1 = fmaf(m, mt[u].z, a1);
          a2 = fmaf(m, mt[u].w, a2);
        }
      }
      for (; i + 8 <= end; i += 8, mp += 3072) {
        float4 mt[8]; unsigned short v[8];
        #pragma unroll
        for (int u = 0; u < 8; ++u) { mt[u] = meta[i + u]; v[u] = mp[u * 384]; }
        #pragma unroll
        for (int u = 0; u < 8; ++u) {
          const float m = bf2f(v[u]);
          a0 = fmaf(m, mt[u].y, a0);
          a1 = fmaf(m, mt[u].z, a1);
          a2 = fmaf(m, mt[u].w, a2);
        }
      }
      for (; i < end; ++i, mp += 384) {
        const float4 mt = meta[i];
        const float m = bf2f(mp[0]);
        a0 = fmaf(m, mt.y, a0); a1 = fmaf(m, mt.z, a1); a2 = fmaf(m, mt.w, a2);
      }
    } else {
      const unsigned short* mp = msg + (size_t)beg * 384 + 320 + ln;
      int i = beg;
      for (; i + 8 <= end; i += 8, mp += 3072) {
        float4 mt[8]; unsigned short v[8];
        #pragma unroll
        for (int u = 0; u < 8; ++u) { mt[u] = meta[i + u]; v[u] = mp[u * 384]; }
        unsigned short x0[8], x1[8], x2[8];
        #pragma unroll
        for (int u = 0; u < 8; ++u) {
          const size_t base = (size_t)__float_as_int(mt[u].x) * NV + ln;
          x0[u] = xv16[base]; x1[u] = xv16[VPLANE + base]; x2[u] = xv16[2 * VPLANE + base];
        }
        #pragma unroll
        for (int u = 0; u < 8; ++u) {
          const float m = bf2f(v[u]);
          a0 = fmaf(m, bf2f(x0[u]), a0);
          a1 = fmaf(m, bf2f(x1[u]), a1);
          a2 = fmaf(m, bf2f(x2[u]), a2);
        }
      }
      for (; i < end; ++i, mp += 384) {
        const float4 mt = meta[i];
        const float m = bf2f(mp[0]);
        const size_t base = (size_t)__float_as_int(mt.x) * NV + ln;
        a0 = fmaf(m, bf2f(xv16[base]), a0);
        a1 = fmaf(m, bf2f(xv16[VPLANE + base]), a1);
        a2 = fmaf(m, bf2f(xv16[2 * VPLANE + base]), a2);
      }
    }
    const float nrm = sqrtf(fmaf(a0, a0, fmaf(a1, a1, a2 * a2)) + 1e-12f);
    const float sg = 1.f / (1.f + __expf(-nrm));
    const int u = (role < 3) ? (role - 1) * 64 + ln : 128 + ln;
    gv16[(size_t)0 * GVPLANE + (size_t)n * 192 + u] = bf16b(a0 * sg);
    gv16[(size_t)1 * GVPLANE + (size_t)n * 192 + u] = bf16b(a1 * sg);
    gv16[(size_t)2 * GVPLANE + (size_t)n * 192 + u] = bf16b(a2 * sg);
  }
}

// ===== node_post_mfma: 32 nodes/block; residual from bf16 copies ==============
__global__ __launch_bounds__(256) void node_post_mfma(
    const unsigned short* __restrict__ gs16, const unsigned short* __restrict__ gv16,
    const unsigned short* __restrict__ WqsP, const unsigned short* __restrict__ WqvP,
    const unsigned short* __restrict__ x_s16, const unsigned short* __restrict__ xv16,
    float* __restrict__ out) {
  __shared__ __align__(16) unsigned short gsA[32 * 200];
  __shared__ __align__(16) unsigned short gvA[3][32 * 200];
  const int n0 = blockIdx.x * 32;
  const int t = threadIdx.x;
  const int lane = t & 63;
  const int w = t >> 6;
  const int l15 = lane & 15;
  const int l4 = lane >> 4;

  {
    const unsigned short* sp = gs16 + (size_t)n0 * 192;
    for (int idx = t; idx < 768; idx += 256) {
      const int row = idx / 24, ch = idx - row * 24;
      *(u16x8*)&gsA[row * 200 + ch * 8] = *(const u16x8*)&sp[row * 192 + ch * 8];
    }
    #pragma unroll
    for (int c = 0; c < 3; ++c) {
      const unsigned short* vp = gv16 + (size_t)c * GVPLANE + (size_t)n0 * 192;
      for (int idx = t; idx < 768; idx += 256) {
        const int row = idx / 24, ch = idx - row * 24;
        *(u16x8*)&gvA[c][row * 200 + ch * 8] = *(const u16x8*)&vp[row * 192 + ch * 8];
      }
    }
  }
  __syncthreads();

  f32x4 accS[2][2];
  f32x4 accV[3][2];
  #pragma unroll
  for (int j = 0; j < 2; ++j)
    #pragma unroll
    for (int mt = 0; mt < 2; ++mt) accS[j][mt] = (f32x4){0.f, 0.f, 0.f, 0.f};
  #pragma unroll
  for (int c = 0; c < 3; ++c)
    #pragma unroll
    for (int mt = 0; mt < 2; ++mt) accV[c][mt] = (f32x4){0.f, 0.f, 0.f, 0.f};

  #pragma unroll
  for (int kc = 0; kc < 6; ++kc) {
    bf16x8 aS[2], aV[3][2];
    #pragma unroll
    for (int mt = 0; mt < 2; ++mt)
      aS[mt] = *(const bf16x8*)&gsA[(mt * 16 + l15) * 200 + kc * 32 + l4 * 8];
    #pragma unroll
    for (int c = 0; c < 3; ++c)
      #pragma unroll
      for (int mt = 0; mt < 2; ++mt)
        aV[c][mt] = *(const bf16x8*)&gvA[c][(mt * 16 + l15) * 200 + kc * 32 + l4 * 8];
    const bf16x8 bS0 = *(const bf16x8*)&WqsP[(((size_t)(w * 2 + 0) * 6 + kc) * 64 + lane) * 8];
    const bf16x8 bS1 = *(const bf16x8*)&WqsP[(((size_t)(w * 2 + 1) * 6 + kc) * 64 + lane) * 8];
    const bf16x8 bV  = *(const bf16x8*)&WqvP[(((size_t)w * 6 + kc) * 64 + lane) * 8];
    #pragma unroll
    for (int mt = 0; mt < 2; ++mt) {
      accS[0][mt] = __builtin_amdgcn_mfma_f32_16x16x32_bf16(aS[mt], bS0, accS[0][mt], 0, 0, 0);
      accS[1][mt] = __builtin_amdgcn_mfma_f32_16x16x32_bf16(aS[mt], bS1, accS[1][mt], 0, 0, 0);
    }
    #pragma unroll
    for (int c = 0; c < 3; ++c)
      #pragma unroll
      for (int mt = 0; mt < 2; ++mt)
        accV[c][mt] = __builtin_amdgcn_mfma_f32_16x16x32_bf16(aV[c][mt], bV, accV[c][mt], 0, 0, 0);
  }

  #pragma unroll
  for (int j = 0; j < 2; ++j) {
    const int col = (w * 2 + j) * 16 + l15;
    #pragma unroll
    for (int mt = 0; mt < 2; ++mt)
      #pragma unroll
      for (int i = 0; i < 4; ++i) {
        const int row = n0 + mt * 16 + l4 * 4 + i;
        out[(size_t)row * 320 + col] =
            bf2f(x_s16[(size_t)row * NS + col]) + accS[j][mt][i];
      }
  }
  {
    const int vch = w * 16 + l15;
    #pragma unroll
    for (int mt = 0; mt < 2; ++mt)
      #pragma unroll
      for (int i = 0; i < 4; ++i) {
        const int row = n0 + mt * 16 + l4 * 4 + i;
        const size_t base = (size_t)row * NV + vch;
        float o0 = bf2f(xv16[base]) + accV[0][mt][i];
        float o1 = bf2f(xv16[VPLANE + base]) + accV[1][mt][i];
        float o2 = bf2f(xv16[2 * VPLANE + base]) + accV[2][mt][i];
        float* op = out + (size_t)row * 320 + NS + vch * 3;
        op[0] = o0; op[1] = o1; op[2] = o2;
      }
  }
}

extern "C" void kernel_launch(void* const* d_in, const int* in_sizes, int n_in,
                              void* d_out, int out_size, void* d_ws, size_t ws_size,
                              hipStream_t stream) {
  const float* node_feat = (const float*)d_in[0];
  const float* edge_attr = (const float*)d_in[1];
  const float* edge_rshs = (const float*)d_in[2];
  const int*   edge_index = (const int*)d_in[3];
  const float* Wps = (const float*)d_in[4];
  const float* bps = (const float*)d_in[5];
  const float* Wpv = (const float*)d_in[6];
  const float* W1  = (const float*)d_in[7];
  const float* b1  = (const float*)d_in[8];
  const float* W2  = (const float*)d_in[9];
  const float* b2  = (const float*)d_in[10];
  const float* Wqs = (const float*)d_in[11];
  const float* Wqv = (const float*)d_in[12];
  float* out = (float*)d_out;

  unsigned short* msg = (unsigned short*)d_ws;                          // 256000*384 bf16
  unsigned short* W1P = msg + (size_t)NEDGE * 384;                      // 4096
  unsigned short* W2P = W1P + 8 * 64 * 8;                               // 49152
  unsigned short* WqsP = W2P + 24 * 4 * 64 * 8;                         // 24576
  unsigned short* WqvP = WqsP + 8 * 6 * 64 * 8;                         // 12288
  unsigned short* WpsP = WqvP + 4 * 6 * 64 * 8;                         // 16384
  unsigned short* WpvP = WpsP + 8 * 4 * 64 * 8;                         // 4096
  unsigned short* x_s16 = WpvP + 4 * 2 * 64 * 8;                        // 2,048,000
  unsigned short* xv16 = x_s16 + (size_t)NNODE * NS;                    // 3,072,000
  unsigned short* gs16 = xv16 + (size_t)3 * VPLANE;                     // 3,072,000
  unsigned short* gv16 = gs16 + (size_t)NNODE * 192;                    // 9,216,000
  float4* meta = (float4*)(gv16 + (size_t)3 * GVPLANE);                 // NEDGE float4
  int* row_start = (int*)(meta + NEDGE);                                // NNODE+1
  int* cursor = row_start + (NNODE + 1);                                // NNODE
  int* perm = cursor + NNODE;                                           // NEDGE

  pack_weights<<<192, 256, 0, stream>>>(W1, W2, Wqs, Wqv, Wps, Wpv,
      W1P, W2P, WqsP, WqvP, WpsP, WpvP, cursor);
  node_pre_mfma<<<NNODE / 32, 256, 0, stream>>>(node_feat, bps, WpsP, WpvP,
      edge_index, cursor, x_s16, xv16);
  scan_kernel<<<1, 256, 0, stream>>>(cursor, row_start, cursor);
  scatter_kernel<<<(NEDGE + 255) / 256, 256, 0, stream>>>(edge_index, edge_rshs,
      cursor, perm, meta);
  edge_mlp_mfma<<<NEDGE / EPB, 256, 0, stream>>>(edge_attr, edge_rshs, edge_index,
      perm, W1P, b1, W2P, b2, x_s16, xv16, msg);
  node_gather<<<NNODE, 256, 0, stream>>>(msg, row_start, meta, xv16, gs16, gv16);
  node_post_mfma<<<NNODE / 32, 256, 0, stream>>>(gs16, gv16, WqsP, WqvP,
      x_s16, xv16, out);
}